// Round 3
// baseline (6053.370 us; speedup 1.0000x reference)
//
#include <hip/hip_runtime.h>

typedef unsigned short u16;
typedef unsigned int u32;
typedef u16 u16x8 __attribute__((ext_vector_type(8)));
typedef __bf16 bf16x8 __attribute__((ext_vector_type(8)));
typedef float f32x4 __attribute__((ext_vector_type(4)));

#define O_N 50000
#define T_N 100000
#define HID 512
#define K1 384
#define BM 128
#define BN 128
#define BK 32
#define LDT 40  // padded LDS stride (u16)

#define OF_F32 1
#define OF_HI 2
#define OF_LO 4

__device__ __forceinline__ u16 f2bf(float f) {
  u32 u = __float_as_uint(f);
  u += 0x7fffu + ((u >> 16) & 1u);
  return (u16)(u >> 16);
}
__device__ __forceinline__ float bf2f(u16 b) {
  return __uint_as_float(((u32)b) << 16);
}
__device__ __forceinline__ f32x4 mfma16(u16x8 a, u16x8 b, f32x4 c) {
  return __builtin_amdgcn_mfma_f32_16x16x32_bf16(
      __builtin_bit_cast(bf16x8, a), __builtin_bit_cast(bf16x8, b), c, 0, 0, 0);
}
__device__ __forceinline__ float wave_sum(float v) {
#pragma unroll
  for (int m = 32; m >= 1; m >>= 1) v += __shfl_xor(v, m, 64);
  return v;
}

// C[M x N] = act(A @ B + bias_f32). B given as bf16 hi(+lo) planes in BT form [N][K].
// AMODE: 0 = A bf16 (u16*); 1 = A fp32 rows, split in stage; 2 = gathered fp32 t_in
//        rows [obj[s]|pred|obj[o]], split in stage; 3 = A bf16 hi/lo planes.
// BSPLIT: stage B lo plane, add Ah*Bl term. Split: acc = Ah*Bh (+ Al*Bh) (+ Ah*Bl).
template <int AMODE, int BSPLIT, int RELU, int OFLAGS>
__global__ __launch_bounds__(256) void gemm_k(
    const void* __restrict__ Ap, const u16* __restrict__ Apl,
    const u16* __restrict__ Bph, const u16* __restrict__ Bpl,
    const float* __restrict__ biasf,
    float* __restrict__ Cf, u16* __restrict__ Ch, u16* __restrict__ Cl,
    int M, int N, int K, int lda, int ldc,
    const int* __restrict__ edges, const float* __restrict__ objf,
    const float* __restrict__ predf, int r0) {
  const bool ASPLIT = (AMODE == 1 || AMODE == 2 || AMODE == 3);
  __shared__ u16 Ah[BM * LDT];
  __shared__ u16 Al[(AMODE == 1 || AMODE == 2 || AMODE == 3) ? BM * LDT : 8];
  __shared__ u16 Bh[BN * LDT];
  __shared__ u16 Bl[BSPLIT ? BN * LDT : 8];

  const int tid = threadIdx.x;
  const int lane = tid & 63;
  const int wave = tid >> 6;
  const int wm = (wave >> 1) * 64;
  const int wn = (wave & 1) * 64;
  const int m0 = blockIdx.x * BM;
  const int n0 = blockIdx.y * BN;
  const int sr = tid >> 1;        // staged tile row
  const int sh = (tid & 1) * 16;  // k-offset half

  f32x4 acc[4][4] = {};

  for (int k0 = 0; k0 < K; k0 += BK) {
    __syncthreads();
    // ---- stage A ----
    if (AMODE == 0) {
      u16x8 v0 = {0, 0, 0, 0, 0, 0, 0, 0}, v1 = {0, 0, 0, 0, 0, 0, 0, 0};
      if (m0 + sr < M) {
        const u16* src = (const u16*)Ap + (size_t)(m0 + sr) * lda + k0 + sh;
        v0 = *(const u16x8*)src;
        v1 = *(const u16x8*)(src + 8);
      }
      *(u16x8*)&Ah[sr * LDT + sh] = v0;
      *(u16x8*)&Ah[sr * LDT + sh + 8] = v1;
    } else if (AMODE == 3) {
      u16x8 h0 = {0, 0, 0, 0, 0, 0, 0, 0}, h1 = h0, l0 = h0, l1 = h0;
      if (m0 + sr < M) {
        size_t base = (size_t)(m0 + sr) * lda + k0 + sh;
        h0 = *(const u16x8*)((const u16*)Ap + base);
        h1 = *(const u16x8*)((const u16*)Ap + base + 8);
        l0 = *(const u16x8*)(Apl + base);
        l1 = *(const u16x8*)(Apl + base + 8);
      }
      *(u16x8*)&Ah[sr * LDT + sh] = h0;
      *(u16x8*)&Ah[sr * LDT + sh + 8] = h1;
      *(u16x8*)&Al[sr * LDT + sh] = l0;
      *(u16x8*)&Al[sr * LDT + sh + 8] = l1;
    } else {  // AMODE 1 or 2: fp32 source, split into hi/lo
      float vals[16];
      if (m0 + sr < M) {
        const float* src;
        if (AMODE == 1) {
          src = (const float*)Ap + (size_t)(m0 + sr) * lda + k0 + sh;
        } else {
          int gr = r0 + m0 + sr;
          int col = k0 + sh;  // 16-col segment inside one source (128|128|128)
          if (col < 128) src = objf + (size_t)edges[gr * 2] * 128 + col;
          else if (col < 256) src = predf + (size_t)gr * 128 + (col - 128);
          else src = objf + (size_t)edges[gr * 2 + 1] * 128 + (col - 256);
        }
        const f32x4* s4 = (const f32x4*)src;
        f32x4 a0 = s4[0], a1 = s4[1], a2 = s4[2], a3 = s4[3];
#pragma unroll
        for (int i = 0; i < 4; i++) {
          vals[i] = a0[i]; vals[4 + i] = a1[i]; vals[8 + i] = a2[i]; vals[12 + i] = a3[i];
        }
      } else {
#pragma unroll
        for (int i = 0; i < 16; i++) vals[i] = 0.f;
      }
      u16x8 h0, h1, l0, l1;
#pragma unroll
      for (int i = 0; i < 8; i++) {
        u16 hb = f2bf(vals[i]);
        h0[i] = hb; l0[i] = f2bf(vals[i] - bf2f(hb));
        u16 hb2 = f2bf(vals[8 + i]);
        h1[i] = hb2; l1[i] = f2bf(vals[8 + i] - bf2f(hb2));
      }
      *(u16x8*)&Ah[sr * LDT + sh] = h0;
      *(u16x8*)&Ah[sr * LDT + sh + 8] = h1;
      *(u16x8*)&Al[sr * LDT + sh] = l0;
      *(u16x8*)&Al[sr * LDT + sh + 8] = l1;
    }
    // ---- stage B ----
    {
      size_t base = (size_t)(n0 + sr) * K + k0 + sh;
      u16x8 b0 = *(const u16x8*)(Bph + base);
      u16x8 b1 = *(const u16x8*)(Bph + base + 8);
      *(u16x8*)&Bh[sr * LDT + sh] = b0;
      *(u16x8*)&Bh[sr * LDT + sh + 8] = b1;
      if (BSPLIT) {
        u16x8 c0 = *(const u16x8*)(Bpl + base);
        u16x8 c1 = *(const u16x8*)(Bpl + base + 8);
        *(u16x8*)&Bl[sr * LDT + sh] = c0;
        *(u16x8*)&Bl[sr * LDT + sh + 8] = c1;
      }
    }
    __syncthreads();
    // ---- fragments + MFMA ----
    const int fr = lane & 15;
    const int q8 = (lane >> 4) * 8;
    u16x8 af[4], bf[4];
#pragma unroll
    for (int i = 0; i < 4; i++) af[i] = *(const u16x8*)&Ah[(wm + i * 16 + fr) * LDT + q8];
#pragma unroll
    for (int j = 0; j < 4; j++) bf[j] = *(const u16x8*)&Bh[(wn + j * 16 + fr) * LDT + q8];
#pragma unroll
    for (int i = 0; i < 4; i++)
#pragma unroll
      for (int j = 0; j < 4; j++) acc[i][j] = mfma16(af[i], bf[j], acc[i][j]);
    if (ASPLIT) {
      u16x8 alf[4];
#pragma unroll
      for (int i = 0; i < 4; i++) alf[i] = *(const u16x8*)&Al[(wm + i * 16 + fr) * LDT + q8];
#pragma unroll
      for (int i = 0; i < 4; i++)
#pragma unroll
        for (int j = 0; j < 4; j++) acc[i][j] = mfma16(alf[i], bf[j], acc[i][j]);
    }
    if (BSPLIT) {
      u16x8 blf[4];
#pragma unroll
      for (int j = 0; j < 4; j++) blf[j] = *(const u16x8*)&Bl[(wn + j * 16 + fr) * LDT + q8];
#pragma unroll
      for (int i = 0; i < 4; i++)
#pragma unroll
        for (int j = 0; j < 4; j++) acc[i][j] = mfma16(af[i], blf[j], acc[i][j]);
    }
  }
  // ---- epilogue: C/D layout col=lane&15, row=(lane>>4)*4+reg (m89/m91 verified) ----
  const int fc = lane & 15;
  const int fr4 = (lane >> 4) * 4;
#pragma unroll
  for (int j = 0; j < 4; j++) {
    int col = n0 + wn + j * 16 + fc;
    float bv = biasf ? biasf[col] : 0.f;
#pragma unroll
    for (int i = 0; i < 4; i++) {
      int rbase = m0 + wm + i * 16 + fr4;
#pragma unroll
      for (int rr = 0; rr < 4; rr++) {
        int row = rbase + rr;
        if (row < M) {
          float v = acc[i][j][rr] + bv;
          if (RELU) v = fmaxf(v, 0.f);
          size_t ci = (size_t)row * ldc + col;
          if (OFLAGS & OF_F32) Cf[ci] = v;
          if (OFLAGS & OF_HI) {
            u16 h = f2bf(v);
            Ch[ci] = h;
            if (OFLAGS & OF_LO) Cl[ci] = f2bf(v - bf2f(h));
          }
        }
      }
    }
  }
}

// fp32 [K][N] -> bf16 hi(+lo) planes in BT form [N][K]. outl may be null.
__global__ void k_convT(const float* __restrict__ in, u16* __restrict__ outh,
                        u16* __restrict__ outl, int K, int N) {
  int idx = blockIdx.x * 256 + threadIdx.x;
  if (idx >= K * N) return;
  int n = idx / K, k = idx % K;
  float v = in[(size_t)k * N + n];
  u16 h = f2bf(v);
  outh[idx] = h;
  if (outl) outl[idx] = f2bf(v - bf2f(h));
}

// fp32 -> bf16 hi/lo planes, elementwise
__global__ void k_conv(const float* __restrict__ in, u16* __restrict__ outh,
                       u16* __restrict__ outl, int n) {
  int idx = blockIdx.x * 256 + threadIdx.x;
  if (idx >= n) return;
  float v = in[idx];
  u16 h = f2bf(v);
  outh[idx] = h;
  if (outl) outl[idx] = f2bf(v - bf2f(h));
}

__global__ void k_zs(const float* __restrict__ pp, const float* __restrict__ simb,
                     float* __restrict__ zs, int rows) {
  int o = blockIdx.x * 4 + (threadIdx.x >> 6);
  int lane = threadIdx.x & 63;
  if (o >= rows) return;
  const f32x4* row = (const f32x4*)(pp + (size_t)o * HID);
  const f32x4* sb = (const f32x4*)(simb + lane * 8);
  f32x4 v0 = row[lane * 2], v1 = row[lane * 2 + 1];
  f32x4 b0 = sb[0], b1 = sb[1];
  float d = v0[0] * b0[0] + v0[1] * b0[1] + v0[2] * b0[2] + v0[3] * b0[3] +
            v1[0] * b1[0] + v1[1] * b1[1] + v1[2] * b1[2] + v1[3] * b1[3];
  d = wave_sum(d);
  if (lane == 0) zs[o] = d;
}

__global__ void k_count(const int* __restrict__ edges, int* __restrict__ cnt) {
  int e = blockIdx.x * 256 + threadIdx.x;
  if (e >= 2 * T_N) return;
  int c = (e < T_N) ? edges[e * 2 + 0] : edges[(e - T_N) * 2 + 1];
  atomicAdd(cnt + c, 1);
}

__global__ void k_scan_a(const int* __restrict__ cnt, int* __restrict__ incl,
                         int* __restrict__ bsum) {
  __shared__ int sb[1024];
  int i = blockIdx.x * 1024 + threadIdx.x;
  int v = (i < O_N) ? cnt[i] : 0;
  sb[threadIdx.x] = v;
  __syncthreads();
  for (int ofs = 1; ofs < 1024; ofs <<= 1) {
    int t = (threadIdx.x >= ofs) ? sb[threadIdx.x - ofs] : 0;
    __syncthreads();
    sb[threadIdx.x] += t;
    __syncthreads();
  }
  if (i < O_N) incl[i] = sb[threadIdx.x];
  if (threadIdx.x == 1023) bsum[blockIdx.x] = sb[1023];
}

__global__ void k_scan_b(const int* __restrict__ bsum, int* __restrict__ bpre, int nb) {
  if (threadIdx.x == 0 && blockIdx.x == 0) {
    int run = 0;
    for (int b = 0; b < nb; b++) { bpre[b] = run; run += bsum[b]; }
  }
}

__global__ void k_scan_c(const int* __restrict__ incl, const int* __restrict__ cnt,
                         const int* __restrict__ bpre, int* __restrict__ excl,
                         int* __restrict__ cursor) {
  int i = blockIdx.x * 1024 + threadIdx.x;
  if (i >= O_N) return;
  int ex = incl[i] - cnt[i] + bpre[blockIdx.x];
  excl[i] = ex;
  cursor[i] = ex;
}

__global__ void k_fill(const int* __restrict__ edges, int* __restrict__ cursor,
                       int* __restrict__ csr) {
  int e = blockIdx.x * 256 + threadIdx.x;
  if (e >= 2 * T_N) return;
  int c = (e < T_N) ? edges[e * 2 + 0] : edges[(e - T_N) * 2 + 1];
  int pos = atomicAdd(cursor + c, 1);
  csr[pos] = e;
}

// phase M scores. AF32=1: s = (cand_hi+cand_lo) . aux_f32 + zs[c] (exact aux; no
// B2 correction pass needed). AF32=0: legacy hi-plane approx (corrected by k_fix).
template <int AF32>
__global__ void k_scores(const u16* __restrict__ newShi, const u16* __restrict__ newOhi,
                         const u16* __restrict__ Slo, const u16* __restrict__ Olo,
                         const u16* __restrict__ auxhi, const float* __restrict__ auxf,
                         const float* __restrict__ zs,
                         const int* __restrict__ edges, float* __restrict__ scores,
                         int r0, int rows) {
  int idx = blockIdx.x * 4 + (threadIdx.x >> 6);
  int lane = threadIdx.x & 63;
  int rl = idx >> 1, side = idx & 1;
  if (rl >= rows) return;
  int grow = r0 + rl;
  int c = edges[grow * 2 + side];
  u16x8 ch = *(const u16x8*)((side ? newOhi : newShi) + (size_t)grow * HID + lane * 8);
  u16x8 cl = *(const u16x8*)((side ? Olo : Slo) + (size_t)rl * HID + lane * 8);
  float d = 0.f;
  if (AF32) {
    const f32x4* ap = (const f32x4*)(auxf + (size_t)c * HID + lane * 8);
    f32x4 a0 = ap[0], a1 = ap[1];
#pragma unroll
    for (int k = 0; k < 4; k++) {
      d += (bf2f(ch[k]) + bf2f(cl[k])) * a0[k];
      d += (bf2f(ch[4 + k]) + bf2f(cl[4 + k])) * a1[k];
    }
  } else {
    u16x8 ah = *(const u16x8*)(auxhi + (size_t)c * HID + lane * 8);
#pragma unroll
    for (int k = 0; k < 8; k++) d += (bf2f(ch[k]) + bf2f(cl[k])) * bf2f(ah[k]);
  }
  d = wave_sum(d);
  if (lane == 0) scores[(side ? T_N : 0) + grow] = d + zs[c];
}

// legacy phase B2: scores[e] += cand_hi . (auxf - auxhi), per O-chunk
__global__ void k_fix(const u16* __restrict__ newShi, const u16* __restrict__ newOhi,
                      const u16* __restrict__ auxhi, const float* __restrict__ auxf,
                      const int* __restrict__ csr, const int* __restrict__ excl,
                      const int* __restrict__ cnt, float* __restrict__ scores,
                      int q0, int rows) {
  int ol = blockIdx.x * 4 + (threadIdx.x >> 6);
  int lane = threadIdx.x & 63;
  if (ol >= rows) return;
  int o = q0 + ol;
  int off = excl[o], deg = cnt[o];
  if (deg == 0) return;
  const f32x4* afp = (const f32x4*)(auxf + (size_t)ol * HID + lane * 8);
  f32x4 af0 = afp[0], af1 = afp[1];
  u16x8 ah = *(const u16x8*)(auxhi + (size_t)o * HID + lane * 8);
  float al[8];
#pragma unroll
  for (int k = 0; k < 4; k++) {
    al[k] = af0[k] - bf2f(ah[k]);
    al[4 + k] = af1[k] - bf2f(ah[4 + k]);
  }
  for (int i = 0; i < deg; i++) {
    int e = csr[off + i];
    const u16* cand =
        (e < T_N) ? newShi + (size_t)e * HID : newOhi + (size_t)(e - T_N) * HID;
    u16x8 ch = *(const u16x8*)(cand + lane * 8);
    float d = 0.f;
#pragma unroll
    for (int k = 0; k < 8; k++) d += bf2f(ch[k]) * al[k];
    d = wave_sum(d);
    if (lane == 0) scores[e] += d;  // each edge owned by exactly one object: no race
  }
}

__global__ void k_pool(const u16* __restrict__ newShi, const u16* __restrict__ newOhi,
                       const float* __restrict__ scores, const float* __restrict__ zs,
                       const int* __restrict__ csr, const int* __restrict__ excl,
                       const int* __restrict__ cnt, float* __restrict__ pooledf,
                       int q0, int rows) {
  int ol = blockIdx.x * 4 + (threadIdx.x >> 6);
  int lane = threadIdx.x & 63;
  if (ol >= rows) return;
  int o = q0 + ol;
  int off = excl[o], deg = cnt[o];
  float zso = zs[o];
  float m = zso;
  for (int base = 0; base < deg; base += 64) {
    float s = (base + lane < deg) ? scores[csr[off + base + lane]] : -3.4e38f;
    m = fmaxf(m, s);
  }
#pragma unroll
  for (int x = 32; x >= 1; x >>= 1) m = fmaxf(m, __shfl_xor(m, x, 64));
  float denom = __expf(zso - m);
  float acc[8] = {0, 0, 0, 0, 0, 0, 0, 0};
  for (int i = 0; i < deg; i++) {
    int e = csr[off + i];
    float w = __expf(scores[e] - m);
    denom += w;
    const u16* cand =
        (e < T_N) ? newShi + (size_t)e * HID : newOhi + (size_t)(e - T_N) * HID;
    u16x8 cv = *(const u16x8*)(cand + lane * 8);
#pragma unroll
    for (int k = 0; k < 8; k++) acc[k] += w * bf2f(cv[k]);
  }
  float inv = 1.0f / denom;
  f32x4 o0, o1;
#pragma unroll
  for (int k = 0; k < 4; k++) {
    o0[k] = acc[k] * inv;
    o1[k] = acc[4 + k] * inv;
  }
  f32x4* dst = (f32x4*)(pooledf + (size_t)ol * HID + lane * 8);
  dst[0] = o0;
  dst[1] = o1;
}

extern "C" void kernel_launch(void* const* d_in, const int* in_sizes, int n_in,
                              void* d_out, int out_size, void* d_ws, size_t ws_size,
                              hipStream_t stream) {
  const float* objf = (const float*)d_in[0];
  const float* predf = (const float*)d_in[1];
  const int* edges = (const int*)d_in[2];
  const float* n1w1f = (const float*)d_in[3];
  const float* n1b1f = (const float*)d_in[4];
  const float* n1w2f = (const float*)d_in[5];
  const float* n1b2f = (const float*)d_in[6];
  const float* n2w1f = (const float*)d_in[7];
  const float* n2b1f = (const float*)d_in[8];
  const float* n2w2f = (const float*)d_in[9];
  const float* n2b2f = (const float*)d_in[10];
  const float* projwf = (const float*)d_in[11];
  const float* projbf = (const float*)d_in[12];
  const float* simwf = (const float*)d_in[13];
  const float* simbf = (const float*)d_in[14];

  float* out_obj = (float*)d_out;                    // O x 128 fp32
  float* out_p = (float*)d_out + (size_t)O_N * 128;  // T x 128 fp32

  // ---- fp32-aux scheme (no B2/k_fix), footprint-reduced:
  //  persistent = newShi+newOhi (204.8M) + auxf fp32 (102.4M) + tail (~9.43M)
  //  arena (B1/M only) = ws - persistent; phase C aliases the dead auxf region.
  const long long FIXED = 316700000ll;  // 307.2M persistent + 9.43M tail + slack
  long long budget = (long long)ws_size - FIXED;
  const bool useF = budget >= 20000000ll;  // rOa>=3255, rT>=4882

  int rOa, rT, rOb;
  size_t arena_sz;
  if (useF) {
    long long rT_l = budget / 4096;  if (rT_l > 25000) rT_l = 25000;
    long long rOa_l = budget / 6144; if (rOa_l > 12500) rOa_l = 12500;
    rT = (int)(rT_l & ~127ll);
    rOa = (int)(rOa_l & ~127ll);
    rOb = 25000;  // lives in auxf region: 25000*512*6 = 76.8M <= 102.4M
    size_t szB = (size_t)rOa * HID * 12;  // prevH,prevL + ppb f32 + ppH,ppL
    size_t szM = (size_t)rT * HID * 8;    // h1H,h1L + Slo,Olo
    arena_sz = szB > szM ? szB : szM;
  } else {
    if (ws_size >= 400000000ull)      { rOa = 12500; rT = 12500; rOb = 25000; }
    else if (ws_size >= 330000000ull) { rOa = 6250;  rT = 6250;  rOb = 12500; }
    else if (ws_size >= 300000000ull) { rOa = 3125;  rT = 6250;  rOb = 6250;  }
    else                              { rOa = 2048;  rT = 2560;  rOb = 2560;  }
    size_t szB = (size_t)rOa * HID * 12;
    size_t szM = (size_t)rT * HID * 8;
    size_t szC = (size_t)rOb * HID * 6;
    arena_sz = szB > szM ? szB : szM;
    if (szC > arena_sz) arena_sz = szC;
  }
  const int nOa = (O_N + rOa - 1) / rOa;
  const int nT = (T_N + rT - 1) / rT;
  const int nOb = (O_N + rOb - 1) / rOb;

  char* ws = (char*)d_ws;
  size_t off = 0;
  u16* newShi = (u16*)(ws + off); off += (size_t)T_N * HID * 2;  // 102.4 MB
  u16* newOhi = (u16*)(ws + off); off += (size_t)T_N * HID * 2;  // 102.4 MB
  u16* auxhi = nullptr;
  float* auxfAll = nullptr;
  char* auxRegion = ws + off;
  if (useF) { auxfAll = (float*)(ws + off); off += (size_t)O_N * HID * 4; }  // 102.4 MB
  else      { auxhi = (u16*)(ws + off);     off += (size_t)O_N * HID * 2; }  // 51.2 MB
  char* arena = ws + off; off += arena_sz;

  // phase B1 views
  u16* prevH = (u16*)arena;
  u16* prevL = (u16*)(arena + (size_t)rOa * HID * 2);
  float* ppb = (float*)(arena + (size_t)rOa * HID * 4);
  u16* ppH = (u16*)(arena + (size_t)rOa * HID * 8);
  u16* ppL = (u16*)(arena + (size_t)rOa * HID * 10);
  // phase B2 views (legacy fallback only; same rOa chunking)
  u16* prevH2 = (u16*)arena;
  u16* prevL2 = (u16*)(arena + (size_t)rOa * HID * 2);
  u16* ppH2 = (u16*)(arena + (size_t)rOa * HID * 4);
  u16* ppL2 = (u16*)(arena + (size_t)rOa * HID * 6);
  float* auxfC = (float*)(arena + (size_t)rOa * HID * 8);
  // phase M views
  u16* h1H = (u16*)arena;
  u16* h1L = (u16*)(arena + (size_t)rT * HID * 2);
  u16* Slo = (u16*)(arena + (size_t)rT * HID * 4);
  u16* Olo = (u16*)(arena + (size_t)rT * HID * 6);
  // phase C views: useF -> alias the (dead after M) auxf region; else arena
  char* cbase = useF ? auxRegion : arena;
  float* pooledf = (float*)cbase;
  u16* h2c = (u16*)(cbase + (size_t)rOb * HID * 4);

  float* scoresb = (float*)(ws + off); off += (size_t)2 * T_N * 4;
  float* zsb = (float*)(ws + off); off += (size_t)O_N * 4;
  int* cnt = (int*)(ws + off); off += (size_t)O_N * 4;
  int* incl = (int*)(ws + off); off += (size_t)O_N * 4;
  int* excl = (int*)(ws + off); off += (size_t)O_N * 4;
  int* cursor = (int*)(ws + off); off += (size_t)O_N * 4;
  int* csr = (int*)(ws + off); off += (size_t)2 * T_N * 4;
  int* bsum = (int*)(ws + off); off += 4096;
  int* bpre = (int*)(ws + off); off += 4096;
  u16* w1TH = (u16*)(ws + off); off += (size_t)K1 * HID * 2;
  u16* w1TL = (u16*)(ws + off); off += (size_t)K1 * HID * 2;
  u16* w2TH = (u16*)(ws + off); off += (size_t)1152 * HID * 2;
  u16* w2TL = (u16*)(ws + off); off += (size_t)1152 * HID * 2;
  u16* pjTH = (u16*)(ws + off); off += (size_t)128 * HID * 2;
  u16* pjTL = (u16*)(ws + off); off += (size_t)128 * HID * 2;
  u16* swTH = (u16*)(ws + off); off += (size_t)HID * HID * 2;
  u16* swTL = (u16*)(ws + off); off += (size_t)HID * HID * 2;
  u16* swRH = (u16*)(ws + off); off += (size_t)HID * HID * 2;
  u16* swRL = (u16*)(ws + off); off += (size_t)HID * HID * 2;
  u16* a2TH = (u16*)(ws + off); off += (size_t)HID * HID * 2;
  u16* a2TL = (u16*)(ws + off); off += (size_t)HID * HID * 2;
  u16* b2TH = (u16*)(ws + off); off += (size_t)128 * HID * 2;
  u16* b2TL = (u16*)(ws + off); off += (size_t)128 * HID * 2;

  hipMemsetAsync(cnt, 0, O_N * sizeof(int), stream);

  // ---- weight planes ----
  k_convT<<<768, 256, 0, stream>>>(n1w1f, w1TH, w1TL, K1, HID);
  k_convT<<<2304, 256, 0, stream>>>(n1w2f, w2TH, w2TL, HID, 1152);
  k_convT<<<256, 256, 0, stream>>>(projwf, pjTH, pjTL, 128, HID);
  k_convT<<<1024, 256, 0, stream>>>(simwf, swTH, swTL, HID, HID);
  k_conv<<<1024, 256, 0, stream>>>(simwf, swRH, swRL, HID * HID);  // aux B = raw simw
  k_convT<<<1024, 256, 0, stream>>>(n2w1f, a2TH, a2TL, HID, HID);
  k_convT<<<256, 256, 0, stream>>>(n2w2f, b2TH, b2TL, HID, 128);

  // ---- CSR of cand_idx ----
  k_count<<<782, 256, 0, stream>>>(edges, cnt);
  k_scan_a<<<49, 1024, 0, stream>>>(cnt, incl, bsum);
  k_scan_b<<<1, 64, 0, stream>>>(bsum, bpre, 49);
  k_scan_c<<<49, 1024, 0, stream>>>(incl, cnt, bpre, excl, cursor);
  k_fill<<<782, 256, 0, stream>>>(edges, cursor, csr);

  // ---- phase B1: prev -> pp (+zs) -> aux, O-chunks ----
  for (int ci = 0; ci < nOa; ci++) {
    int q0 = ci * rOa;
    int rows = (q0 + rOa <= O_N) ? rOa : (O_N - q0);
    dim3 g4((rows + BM - 1) / BM, 4);
    gemm_k<1, 1, 0, OF_HI | OF_LO><<<g4, 256, 0, stream>>>(
        objf + (size_t)q0 * 128, nullptr, pjTH, pjTL, projbf,
        nullptr, prevH, prevL, rows, HID, 128, 128, HID, nullptr, nullptr, nullptr, 0);
    gemm_k<3, 1, 0, OF_F32 | OF_HI | OF_LO><<<g4, 256, 0, stream>>>(
        prevH, prevL, swTH, swTL, simbf,
        ppb, ppH, ppL, rows, HID, HID, HID, HID, nullptr, nullptr, nullptr, 0);
    if (useF) {
      gemm_k<3, 1, 0, OF_F32><<<g4, 256, 0, stream>>>(
          ppH, ppL, swRH, swRL, nullptr,
          auxfAll + (size_t)q0 * HID, nullptr, nullptr, rows, HID, HID, HID, HID,
          nullptr, nullptr, nullptr, 0);
    } else {
      gemm_k<3, 1, 0, OF_HI><<<g4, 256, 0, stream>>>(
          ppH, ppL, swRH, swRL, nullptr,
          nullptr, auxhi + (size_t)q0 * HID, nullptr, rows, HID, HID, HID, HID,
          nullptr, nullptr, nullptr, 0);
    }
    k_zs<<<(rows + 3) / 4, 256, 0, stream>>>(ppb, simbf, zsb + q0, rows);
  }

  // ---- phase M: MLP1 + s1 scores, T-chunks ----
  for (int ci = 0; ci < nT; ci++) {
    int r0 = ci * rT;
    int rows = (r0 + rT <= T_N) ? rT : (T_N - r0);
    dim3 g4((rows + BM - 1) / BM, 4);
    dim3 g1((rows + BM - 1) / BM, 1);
    gemm_k<2, 1, 1, OF_HI | OF_LO><<<g4, 256, 0, stream>>>(
        nullptr, nullptr, w1TH, w1TL, n1b1f,
        nullptr, h1H, h1L, rows, HID, K1, 0, HID, edges, objf, predf, r0);
    gemm_k<3, 1, 1, OF_HI | OF_LO><<<g4, 256, 0, stream>>>(
        h1H, h1L, w2TH, w2TL, n1b2f,
        nullptr, newShi + (size_t)r0 * HID, Slo, rows, HID, HID, HID, HID,
        nullptr, nullptr, nullptr, 0);
    gemm_k<3, 1, 1, OF_F32><<<g1, 256, 0, stream>>>(
        h1H, h1L, w2TH + (size_t)512 * HID, w2TL + (size_t)512 * HID, n1b2f + 512,
        out_p + (size_t)r0 * 128, nullptr, nullptr, rows, 128, HID, HID, 128,
        nullptr, nullptr, nullptr, 0);
    gemm_k<3, 1, 1, OF_HI | OF_LO><<<g4, 256, 0, stream>>>(
        h1H, h1L, w2TH + (size_t)640 * HID, w2TL + (size_t)640 * HID, n1b2f + 640,
        nullptr, newOhi + (size_t)r0 * HID, Olo, rows, HID, HID, HID, HID,
        nullptr, nullptr, nullptr, 0);
    if (useF) {
      k_scores<1><<<(2 * rows + 3) / 4, 256, 0, stream>>>(
          newShi, newOhi, Slo, Olo, nullptr, auxfAll, zsb, edges, scoresb, r0, rows);
    } else {
      k_scores<0><<<(2 * rows + 3) / 4, 256, 0, stream>>>(
          newShi, newOhi, Slo, Olo, auxhi, nullptr, zsb, edges, scoresb, r0, rows);
    }
  }

  // ---- phase B2 (legacy fallback only): recompute aux in fp32, correct scores ----
  if (!useF) {
    for (int ci = 0; ci < nOa; ci++) {
      int q0 = ci * rOa;
      int rows = (q0 + rOa <= O_N) ? rOa : (O_N - q0);
      dim3 g4((rows + BM - 1) / BM, 4);
      gemm_k<1, 1, 0, OF_HI | OF_LO><<<g4, 256, 0, stream>>>(
          objf + (size_t)q0 * 128, nullptr, pjTH, pjTL, projbf,
          nullptr, prevH2, prevL2, rows, HID, 128, 128, HID, nullptr, nullptr, nullptr, 0);
      gemm_k<3, 1, 0, OF_HI | OF_LO><<<g4, 256, 0, stream>>>(
          prevH2, prevL2, swTH, swTL, simbf,
          nullptr, ppH2, ppL2, rows, HID, HID, HID, HID, nullptr, nullptr, nullptr, 0);
      gemm_k<3, 1, 0, OF_F32><<<g4, 256, 0, stream>>>(
          ppH2, ppL2, swRH, swRL, nullptr,
          auxfC, nullptr, nullptr, rows, HID, HID, HID, HID, nullptr, nullptr, nullptr, 0);
      k_fix<<<(rows + 3) / 4, 256, 0, stream>>>(
          newShi, newOhi, auxhi, auxfC, csr, excl, cnt, scoresb, q0, rows);
    }
  }

  // ---- phase C: pool -> MLP2, O-chunks ----
  for (int ci = 0; ci < nOb; ci++) {
    int q0 = ci * rOb;
    int rows = (q0 + rOb <= O_N) ? rOb : (O_N - q0);
    dim3 g4((rows + BM - 1) / BM, 4);
    dim3 g1((rows + BM - 1) / BM, 1);
    k_pool<<<(rows + 3) / 4, 256, 0, stream>>>(
        newShi, newOhi, scoresb, zsb, csr, excl, cnt, pooledf, q0, rows);
    gemm_k<1, 1, 1, OF_HI><<<g4, 256, 0, stream>>>(
        pooledf, nullptr, a2TH, a2TL, n2b1f,
        nullptr, h2c, nullptr, rows, HID, HID, HID, HID, nullptr, nullptr, nullptr, 0);
    gemm_k<0, 1, 1, OF_F32><<<g1, 256, 0, stream>>>(
        h2c, nullptr, b2TH, b2TL, n2b2f,
        out_obj + (size_t)q0 * 128, nullptr, nullptr, rows, 128, HID, HID, 128,
        nullptr, nullptr, nullptr, 0);
  }

  (void)in_sizes; (void)n_in; (void)out_size;
}

// Round 4
// 2540.774 us; speedup vs baseline: 2.3825x; 2.3825x over previous
//
#include <hip/hip_runtime.h>

typedef unsigned short u16;
typedef unsigned int u32;
typedef u16 u16x8 __attribute__((ext_vector_type(8)));
typedef __bf16 bf16x8 __attribute__((ext_vector_type(8)));
typedef float f32x4 __attribute__((ext_vector_type(4)));

#define O_N 50000
#define T_N 100000
#define HID 512
#define K1 384
#define BM 128
#define BN 128
#define BK 32
#define LDT 40  // padded LDS stride (u16)

#define OF_F32 1
#define OF_HI 2
#define OF_LO 4

__device__ __forceinline__ u16 f2bf(float f) {
  u32 u = __float_as_uint(f);
  u += 0x7fffu + ((u >> 16) & 1u);
  return (u16)(u >> 16);
}
__device__ __forceinline__ float bf2f(u16 b) {
  return __uint_as_float(((u32)b) << 16);
}
__device__ __forceinline__ f32x4 mfma16(u16x8 a, u16x8 b, f32x4 c) {
  return __builtin_amdgcn_mfma_f32_16x16x32_bf16(
      __builtin_bit_cast(bf16x8, a), __builtin_bit_cast(bf16x8, b), c, 0, 0, 0);
}
__device__ __forceinline__ float wave_sum(float v) {
#pragma unroll
  for (int m = 32; m >= 1; m >>= 1) v += __shfl_xor(v, m, 64);
  return v;
}

// C[M x N] = act(A @ B + bias_f32). B given as bf16 hi(+lo) planes in BT form [N][K].
// AMODE: 0 = A bf16 (u16*); 1 = A fp32 rows, split in stage; 2 = gathered fp32 t_in
//        rows [obj[s]|pred|obj[o]], split in stage; 3 = A bf16 hi/lo planes.
// BSPLIT: stage B lo plane, add Ah*Bl term. Split: acc = Ah*Bh (+ Al*Bh) (+ Ah*Bl).
template <int AMODE, int BSPLIT, int RELU, int OFLAGS>
__global__ __launch_bounds__(256) void gemm_k(
    const void* __restrict__ Ap, const u16* __restrict__ Apl,
    const u16* __restrict__ Bph, const u16* __restrict__ Bpl,
    const float* __restrict__ biasf,
    float* __restrict__ Cf, u16* __restrict__ Ch, u16* __restrict__ Cl,
    int M, int N, int K, int lda, int ldc,
    const int* __restrict__ edges, const float* __restrict__ objf,
    const float* __restrict__ predf, int r0) {
  const bool ASPLIT = (AMODE == 1 || AMODE == 2 || AMODE == 3);
  __shared__ u16 Ah[BM * LDT];
  __shared__ u16 Al[(AMODE == 1 || AMODE == 2 || AMODE == 3) ? BM * LDT : 8];
  __shared__ u16 Bh[BN * LDT];
  __shared__ u16 Bl[BSPLIT ? BN * LDT : 8];

  const int tid = threadIdx.x;
  const int lane = tid & 63;
  const int wave = tid >> 6;
  const int wm = (wave >> 1) * 64;
  const int wn = (wave & 1) * 64;
  const int m0 = blockIdx.x * BM;
  const int n0 = blockIdx.y * BN;
  const int sr = tid >> 1;        // staged tile row
  const int sh = (tid & 1) * 16;  // k-offset half

  f32x4 acc[4][4] = {};

  for (int k0 = 0; k0 < K; k0 += BK) {
    __syncthreads();
    // ---- stage A ----
    if (AMODE == 0) {
      u16x8 v0 = {0, 0, 0, 0, 0, 0, 0, 0}, v1 = {0, 0, 0, 0, 0, 0, 0, 0};
      if (m0 + sr < M) {
        const u16* src = (const u16*)Ap + (size_t)(m0 + sr) * lda + k0 + sh;
        v0 = *(const u16x8*)src;
        v1 = *(const u16x8*)(src + 8);
      }
      *(u16x8*)&Ah[sr * LDT + sh] = v0;
      *(u16x8*)&Ah[sr * LDT + sh + 8] = v1;
    } else if (AMODE == 3) {
      u16x8 h0 = {0, 0, 0, 0, 0, 0, 0, 0}, h1 = h0, l0 = h0, l1 = h0;
      if (m0 + sr < M) {
        size_t base = (size_t)(m0 + sr) * lda + k0 + sh;
        h0 = *(const u16x8*)((const u16*)Ap + base);
        h1 = *(const u16x8*)((const u16*)Ap + base + 8);
        l0 = *(const u16x8*)(Apl + base);
        l1 = *(const u16x8*)(Apl + base + 8);
      }
      *(u16x8*)&Ah[sr * LDT + sh] = h0;
      *(u16x8*)&Ah[sr * LDT + sh + 8] = h1;
      *(u16x8*)&Al[sr * LDT + sh] = l0;
      *(u16x8*)&Al[sr * LDT + sh + 8] = l1;
    } else {  // AMODE 1 or 2: fp32 source, split into hi/lo
      float vals[16];
      if (m0 + sr < M) {
        const float* src;
        if (AMODE == 1) {
          src = (const float*)Ap + (size_t)(m0 + sr) * lda + k0 + sh;
        } else {
          int gr = r0 + m0 + sr;
          int col = k0 + sh;  // 16-col segment inside one source (128|128|128)
          if (col < 128) src = objf + (size_t)edges[gr * 2] * 128 + col;
          else if (col < 256) src = predf + (size_t)gr * 128 + (col - 128);
          else src = objf + (size_t)edges[gr * 2 + 1] * 128 + (col - 256);
        }
        const f32x4* s4 = (const f32x4*)src;
        f32x4 a0 = s4[0], a1 = s4[1], a2 = s4[2], a3 = s4[3];
#pragma unroll
        for (int i = 0; i < 4; i++) {
          vals[i] = a0[i]; vals[4 + i] = a1[i]; vals[8 + i] = a2[i]; vals[12 + i] = a3[i];
        }
      } else {
#pragma unroll
        for (int i = 0; i < 16; i++) vals[i] = 0.f;
      }
      u16x8 h0, h1, l0, l1;
#pragma unroll
      for (int i = 0; i < 8; i++) {
        u16 hb = f2bf(vals[i]);
        h0[i] = hb; l0[i] = f2bf(vals[i] - bf2f(hb));
        u16 hb2 = f2bf(vals[8 + i]);
        h1[i] = hb2; l1[i] = f2bf(vals[8 + i] - bf2f(hb2));
      }
      *(u16x8*)&Ah[sr * LDT + sh] = h0;
      *(u16x8*)&Ah[sr * LDT + sh + 8] = h1;
      *(u16x8*)&Al[sr * LDT + sh] = l0;
      *(u16x8*)&Al[sr * LDT + sh + 8] = l1;
    }
    // ---- stage B ----
    {
      size_t base = (size_t)(n0 + sr) * K + k0 + sh;
      u16x8 b0 = *(const u16x8*)(Bph + base);
      u16x8 b1 = *(const u16x8*)(Bph + base + 8);
      *(u16x8*)&Bh[sr * LDT + sh] = b0;
      *(u16x8*)&Bh[sr * LDT + sh + 8] = b1;
      if (BSPLIT) {
        u16x8 c0 = *(const u16x8*)(Bpl + base);
        u16x8 c1 = *(const u16x8*)(Bpl + base + 8);
        *(u16x8*)&Bl[sr * LDT + sh] = c0;
        *(u16x8*)&Bl[sr * LDT + sh + 8] = c1;
      }
    }
    __syncthreads();
    // ---- fragments + MFMA ----
    const int fr = lane & 15;
    const int q8 = (lane >> 4) * 8;
    u16x8 af[4], bf[4];
#pragma unroll
    for (int i = 0; i < 4; i++) af[i] = *(const u16x8*)&Ah[(wm + i * 16 + fr) * LDT + q8];
#pragma unroll
    for (int j = 0; j < 4; j++) bf[j] = *(const u16x8*)&Bh[(wn + j * 16 + fr) * LDT + q8];
#pragma unroll
    for (int i = 0; i < 4; i++)
#pragma unroll
      for (int j = 0; j < 4; j++) acc[i][j] = mfma16(af[i], bf[j], acc[i][j]);
    if (ASPLIT) {
      u16x8 alf[4];
#pragma unroll
      for (int i = 0; i < 4; i++) alf[i] = *(const u16x8*)&Al[(wm + i * 16 + fr) * LDT + q8];
#pragma unroll
      for (int i = 0; i < 4; i++)
#pragma unroll
        for (int j = 0; j < 4; j++) acc[i][j] = mfma16(alf[i], bf[j], acc[i][j]);
    }
    if (BSPLIT) {
      u16x8 blf[4];
#pragma unroll
      for (int j = 0; j < 4; j++) blf[j] = *(const u16x8*)&Bl[(wn + j * 16 + fr) * LDT + q8];
#pragma unroll
      for (int i = 0; i < 4; i++)
#pragma unroll
        for (int j = 0; j < 4; j++) acc[i][j] = mfma16(af[i], blf[j], acc[i][j]);
    }
  }
  // ---- epilogue: C/D layout col=lane&15, row=(lane>>4)*4+reg (m89/m91 verified) ----
  const int fc = lane & 15;
  const int fr4 = (lane >> 4) * 4;
#pragma unroll
  for (int j = 0; j < 4; j++) {
    int col = n0 + wn + j * 16 + fc;
    float bv = biasf ? biasf[col] : 0.f;
#pragma unroll
    for (int i = 0; i < 4; i++) {
      int rbase = m0 + wm + i * 16 + fr4;
#pragma unroll
      for (int rr = 0; rr < 4; rr++) {
        int row = rbase + rr;
        if (row < M) {
          float v = acc[i][j][rr] + bv;
          if (RELU) v = fmaxf(v, 0.f);
          size_t ci = (size_t)row * ldc + col;
          if (OFLAGS & OF_F32) Cf[ci] = v;
          if (OFLAGS & OF_HI) {
            u16 h = f2bf(v);
            Ch[ci] = h;
            if (OFLAGS & OF_LO) Cl[ci] = f2bf(v - bf2f(h));
          }
        }
      }
    }
  }
}

// fp32 [K][N] -> bf16 hi(+lo) planes in BT form [N][K]. outl may be null.
__global__ void k_convT(const float* __restrict__ in, u16* __restrict__ outh,
                        u16* __restrict__ outl, int K, int N) {
  int idx = blockIdx.x * 256 + threadIdx.x;
  if (idx >= K * N) return;
  int n = idx / K, k = idx % K;
  float v = in[(size_t)k * N + n];
  u16 h = f2bf(v);
  outh[idx] = h;
  if (outl) outl[idx] = f2bf(v - bf2f(h));
}

// fp32 -> bf16 hi/lo planes, elementwise
__global__ void k_conv(const float* __restrict__ in, u16* __restrict__ outh,
                       u16* __restrict__ outl, int n) {
  int idx = blockIdx.x * 256 + threadIdx.x;
  if (idx >= n) return;
  float v = in[idx];
  u16 h = f2bf(v);
  outh[idx] = h;
  if (outl) outl[idx] = f2bf(v - bf2f(h));
}

// ---- weight folding (all fp32, trivial FLOPs) ----
// bf1[n] = sum_k bp[k]*Ws[k][n] + bs[n]
__global__ void k_foldb1(const float* __restrict__ bp, const float* __restrict__ Ws,
                         const float* __restrict__ bs, float* __restrict__ bf1) {
  int n = blockIdx.x * 256 + threadIdx.x;
  if (n >= HID) return;
  float s = bs[n];
  for (int k = 0; k < HID; k++) s += bp[k] * Ws[(size_t)k * HID + n];
  bf1[n] = s;
}
// ba[n] = sum_k bf1[k]*Ws[n][k]   (row n of Ws)
__global__ void k_foldba(const float* __restrict__ bf1, const float* __restrict__ Ws,
                         float* __restrict__ ba) {
  int n = blockIdx.x * 256 + threadIdx.x;
  if (n >= HID) return;
  float s = 0.f;
  for (int k = 0; k < HID; k++) s += bf1[k] * Ws[(size_t)n * HID + k];
  ba[n] = s;
}
// wz[m] = sum_n Wf[m][n]*bs[n];  bz = bf1.bs
__global__ void k_foldwz(const float* __restrict__ Wf, const float* __restrict__ bs,
                         const float* __restrict__ bf1, float* __restrict__ wz,
                         float* __restrict__ bz) {
  int m = blockIdx.x * 256 + threadIdx.x;
  if (m < 128) {
    float s = 0.f;
    for (int n = 0; n < HID; n++) s += Wf[(size_t)m * HID + n] * bs[n];
    wz[m] = s;
  }
  if (m == 128) {
    float s = 0.f;
    for (int n = 0; n < HID; n++) s += bf1[n] * bs[n];
    *bz = s;
  }
}
// zs[o] = obj[o].wz + bz   (replaces pp.bs via folding)
__global__ void k_zsm(const float* __restrict__ obj, const float* __restrict__ wz,
                      const float* __restrict__ bz, float* __restrict__ zs, int rows) {
  int o = blockIdx.x * 4 + (threadIdx.x >> 6);
  int lane = threadIdx.x & 63;
  if (o >= rows) return;
  const float2* row = (const float2*)(obj + (size_t)o * 128);
  float2 v = row[lane];
  float2 w = ((const float2*)wz)[lane];
  float d = v.x * w.x + v.y * w.y;
  d = wave_sum(d);
  if (lane == 0) zs[o] = d + *bz;
}

__global__ void k_count(const int* __restrict__ edges, int* __restrict__ cnt) {
  int e = blockIdx.x * 256 + threadIdx.x;
  if (e >= 2 * T_N) return;
  int c = (e < T_N) ? edges[e * 2 + 0] : edges[(e - T_N) * 2 + 1];
  atomicAdd(cnt + c, 1);
}

__global__ void k_scan_a(const int* __restrict__ cnt, int* __restrict__ incl,
                         int* __restrict__ bsum) {
  __shared__ int sb[1024];
  int i = blockIdx.x * 1024 + threadIdx.x;
  int v = (i < O_N) ? cnt[i] : 0;
  sb[threadIdx.x] = v;
  __syncthreads();
  for (int ofs = 1; ofs < 1024; ofs <<= 1) {
    int t = (threadIdx.x >= ofs) ? sb[threadIdx.x - ofs] : 0;
    __syncthreads();
    sb[threadIdx.x] += t;
    __syncthreads();
  }
  if (i < O_N) incl[i] = sb[threadIdx.x];
  if (threadIdx.x == 1023) bsum[blockIdx.x] = sb[1023];
}

__global__ void k_scan_b(const int* __restrict__ bsum, int* __restrict__ bpre, int nb) {
  if (threadIdx.x == 0 && blockIdx.x == 0) {
    int run = 0;
    for (int b = 0; b < nb; b++) { bpre[b] = run; run += bsum[b]; }
  }
}

__global__ void k_scan_c(const int* __restrict__ incl, const int* __restrict__ cnt,
                         const int* __restrict__ bpre, int* __restrict__ excl,
                         int* __restrict__ cursor) {
  int i = blockIdx.x * 1024 + threadIdx.x;
  if (i >= O_N) return;
  int ex = incl[i] - cnt[i] + bpre[blockIdx.x];
  excl[i] = ex;
  cursor[i] = ex;
}

__global__ void k_fill(const int* __restrict__ edges, int* __restrict__ cursor,
                       int* __restrict__ csr) {
  int e = blockIdx.x * 256 + threadIdx.x;
  if (e >= 2 * T_N) return;
  int c = (e < T_N) ? edges[e * 2 + 0] : edges[(e - T_N) * 2 + 1];
  int pos = atomicAdd(cursor + c, 1);
  csr[pos] = e;
}

// phase M scores: s1 = (cand_hi + cand_lo) . aux_hi + zs[c]  (corrected by k_fix)
__global__ void k_scores(const u16* __restrict__ newShi, const u16* __restrict__ newOhi,
                         const u16* __restrict__ Slo, const u16* __restrict__ Olo,
                         const u16* __restrict__ auxhi, const float* __restrict__ zs,
                         const int* __restrict__ edges, float* __restrict__ scores,
                         int r0, int rows) {
  int idx = blockIdx.x * 4 + (threadIdx.x >> 6);
  int lane = threadIdx.x & 63;
  int rl = idx >> 1, side = idx & 1;
  if (rl >= rows) return;
  int grow = r0 + rl;
  int c = edges[grow * 2 + side];
  u16x8 ch = *(const u16x8*)((side ? newOhi : newShi) + (size_t)grow * HID + lane * 8);
  u16x8 cl = *(const u16x8*)((side ? Olo : Slo) + (size_t)rl * HID + lane * 8);
  u16x8 ah = *(const u16x8*)(auxhi + (size_t)c * HID + lane * 8);
  float d = 0.f;
#pragma unroll
  for (int k = 0; k < 8; k++) d += (bf2f(ch[k]) + bf2f(cl[k])) * bf2f(ah[k]);
  d = wave_sum(d);
  if (lane == 0) scores[(side ? T_N : 0) + grow] = d + zs[c];
}

// score fix: scores[e] += cand_hi . (auxf - auxhi), per O-chunk
__global__ void k_fix(const u16* __restrict__ newShi, const u16* __restrict__ newOhi,
                      const u16* __restrict__ auxhi, const float* __restrict__ auxf,
                      const int* __restrict__ csr, const int* __restrict__ excl,
                      const int* __restrict__ cnt, float* __restrict__ scores,
                      int q0, int rows) {
  int ol = blockIdx.x * 4 + (threadIdx.x >> 6);
  int lane = threadIdx.x & 63;
  if (ol >= rows) return;
  int o = q0 + ol;
  int off = excl[o], deg = cnt[o];
  if (deg == 0) return;
  const f32x4* afp = (const f32x4*)(auxf + (size_t)ol * HID + lane * 8);
  f32x4 af0 = afp[0], af1 = afp[1];
  u16x8 ah = *(const u16x8*)(auxhi + (size_t)o * HID + lane * 8);
  float al[8];
#pragma unroll
  for (int k = 0; k < 4; k++) {
    al[k] = af0[k] - bf2f(ah[k]);
    al[4 + k] = af1[k] - bf2f(ah[4 + k]);
  }
  for (int i = 0; i < deg; i++) {
    int e = csr[off + i];
    const u16* cand =
        (e < T_N) ? newShi + (size_t)e * HID : newOhi + (size_t)(e - T_N) * HID;
    u16x8 ch = *(const u16x8*)(cand + lane * 8);
    float d = 0.f;
#pragma unroll
    for (int k = 0; k < 8; k++) d += bf2f(ch[k]) * al[k];
    d = wave_sum(d);
    if (lane == 0) scores[e] += d;  // each edge owned by exactly one object: no race
  }
}

__global__ void k_pool(const u16* __restrict__ newShi, const u16* __restrict__ newOhi,
                       const float* __restrict__ scores, const float* __restrict__ zs,
                       const int* __restrict__ csr, const int* __restrict__ excl,
                       const int* __restrict__ cnt, float* __restrict__ pooledf,
                       int q0, int rows) {
  int ol = blockIdx.x * 4 + (threadIdx.x >> 6);
  int lane = threadIdx.x & 63;
  if (ol >= rows) return;
  int o = q0 + ol;
  int off = excl[o], deg = cnt[o];
  float zso = zs[o];
  float m = zso;
  for (int base = 0; base < deg; base += 64) {
    float s = (base + lane < deg) ? scores[csr[off + base + lane]] : -3.4e38f;
    m = fmaxf(m, s);
  }
#pragma unroll
  for (int x = 32; x >= 1; x >>= 1) m = fmaxf(m, __shfl_xor(m, x, 64));
  float denom = __expf(zso - m);
  float acc[8] = {0, 0, 0, 0, 0, 0, 0, 0};
  for (int i = 0; i < deg; i++) {
    int e = csr[off + i];
    float w = __expf(scores[e] - m);
    denom += w;
    const u16* cand =
        (e < T_N) ? newShi + (size_t)e * HID : newOhi + (size_t)(e - T_N) * HID;
    u16x8 cv = *(const u16x8*)(cand + lane * 8);
#pragma unroll
    for (int k = 0; k < 8; k++) acc[k] += w * bf2f(cv[k]);
  }
  float inv = 1.0f / denom;
  f32x4 o0, o1;
#pragma unroll
  for (int k = 0; k < 4; k++) {
    o0[k] = acc[k] * inv;
    o1[k] = acc[4 + k] * inv;
  }
  f32x4* dst = (f32x4*)(pooledf + (size_t)ol * HID + lane * 8);
  dst[0] = o0;
  dst[1] = o1;
}

extern "C" void kernel_launch(void* const* d_in, const int* in_sizes, int n_in,
                              void* d_out, int out_size, void* d_ws, size_t ws_size,
                              hipStream_t stream) {
  const float* objf = (const float*)d_in[0];
  const float* predf = (const float*)d_in[1];
  const int* edges = (const int*)d_in[2];
  const float* n1w1f = (const float*)d_in[3];
  const float* n1b1f = (const float*)d_in[4];
  const float* n1w2f = (const float*)d_in[5];
  const float* n1b2f = (const float*)d_in[6];
  const float* n2w1f = (const float*)d_in[7];
  const float* n2b1f = (const float*)d_in[8];
  const float* n2w2f = (const float*)d_in[9];
  const float* n2b2f = (const float*)d_in[10];
  const float* projwf = (const float*)d_in[11];
  const float* projbf = (const float*)d_in[12];
  const float* simwf = (const float*)d_in[13];
  const float* simbf = (const float*)d_in[14];

  float* out_obj = (float*)d_out;                    // O x 128 fp32
  float* out_p = (float*)d_out + (size_t)O_N * 128;  // T x 128 fp32

  // ---- weight-folded scheme ----
  // aux = obj @ (Wp@Ws@Ws^T) + (bp@Ws+bs)@Ws^T ; zs = obj.(Wp@Ws@bs) + bf1.bs.
  // prev/pp never materialize; B1 becomes one full-grid K=128 gemm.
  // Persistent: newShi+newOhi (204.8M) + auxhi (51.2M) + tail (~10.5M).
  const long long FIXED = 267000000ll;
  long long budget = (long long)ws_size - FIXED;
  if (budget < 5000000ll) budget = 5000000ll;  // floor (ws>=~272M held in all rounds)
  long long rT_l = budget / 4096;  if (rT_l > 25000) rT_l = 25000;
  int rT = (int)(rT_l & ~127ll);   if (rT < 1280) rT = 1280;
  long long rOb_l = budget / 3072; if (rOb_l > 25000) rOb_l = 25000;
  int rOb = (int)rOb_l;            if (rOb < 1280) rOb = 1280;
  long long rFx_l = budget / 2048; if (rFx_l > 25000) rFx_l = 25000;
  int rFx = (int)rFx_l;            if (rFx < 1280) rFx = 1280;
  const int nT = (T_N + rT - 1) / rT;
  const int nOb = (O_N + rOb - 1) / rOb;
  const int nFx = (O_N + rFx - 1) / rFx;
  size_t arena_sz = (size_t)rT * 4096;
  if ((size_t)rOb * 3072 > arena_sz) arena_sz = (size_t)rOb * 3072;
  if ((size_t)rFx * 2048 > arena_sz) arena_sz = (size_t)rFx * 2048;
  arena_sz = (arena_sz + 4095) & ~(size_t)4095;

  char* ws = (char*)d_ws;
  size_t off = 0;
  u16* newShi = (u16*)(ws + off); off += (size_t)T_N * HID * 2;  // 102.4 MB
  u16* newOhi = (u16*)(ws + off); off += (size_t)T_N * HID * 2;  // 102.4 MB
  u16* auxhi = (u16*)(ws + off);  off += (size_t)O_N * HID * 2;  // 51.2 MB
  char* arena = ws + off; off += arena_sz;

  // phase M views
  u16* h1H = (u16*)arena;
  u16* h1L = (u16*)(arena + (size_t)rT * HID * 2);
  u16* Slo = (u16*)(arena + (size_t)rT * HID * 4);
  u16* Olo = (u16*)(arena + (size_t)rT * HID * 6);
  // fix-phase view
  float* auxfC = (float*)arena;
  // phase C views
  float* pooledf = (float*)arena;
  u16* h2c = (u16*)(arena + (size_t)rOb * HID * 4);

  float* scoresb = (float*)(ws + off); off += (size_t)2 * T_N * 4;
  float* zsb = (float*)(ws + off); off += (size_t)O_N * 4;
  int* cnt = (int*)(ws + off); off += (size_t)O_N * 4;
  int* incl = (int*)(ws + off); off += (size_t)O_N * 4;
  int* excl = (int*)(ws + off); off += (size_t)O_N * 4;
  int* cursor = (int*)(ws + off); off += (size_t)O_N * 4;
  int* csr = (int*)(ws + off); off += (size_t)2 * T_N * 4;
  int* bsum = (int*)(ws + off); off += 4096;
  int* bpre = (int*)(ws + off); off += 4096;
  u16* w1TH = (u16*)(ws + off); off += (size_t)K1 * HID * 2;
  u16* w1TL = (u16*)(ws + off); off += (size_t)K1 * HID * 2;
  u16* w2TH = (u16*)(ws + off); off += (size_t)1152 * HID * 2;
  u16* w2TL = (u16*)(ws + off); off += (size_t)1152 * HID * 2;
  u16* swTH = (u16*)(ws + off); off += (size_t)HID * HID * 2;
  u16* swTL = (u16*)(ws + off); off += (size_t)HID * HID * 2;
  u16* swRH = (u16*)(ws + off); off += (size_t)HID * HID * 2;
  u16* swRL = (u16*)(ws + off); off += (size_t)HID * HID * 2;
  u16* a2TH = (u16*)(ws + off); off += (size_t)HID * HID * 2;
  u16* a2TL = (u16*)(ws + off); off += (size_t)HID * HID * 2;
  u16* b2TH = (u16*)(ws + off); off += (size_t)128 * HID * 2;
  u16* b2TL = (u16*)(ws + off); off += (size_t)128 * HID * 2;
  float* Wf = (float*)(ws + off);  off += (size_t)128 * HID * 4;  // Wp@Ws
  float* Waf = (float*)(ws + off); off += (size_t)128 * HID * 4;  // Wf@Ws^T
  u16* WaTH = (u16*)(ws + off); off += (size_t)HID * 128 * 2;
  u16* WaTL = (u16*)(ws + off); off += (size_t)HID * 128 * 2;
  float* bf1 = (float*)(ws + off); off += 2048;
  float* baf = (float*)(ws + off); off += 2048;
  float* wzf = (float*)(ws + off); off += 512;
  float* bzf = (float*)(ws + off); off += 16;

  hipMemsetAsync(cnt, 0, O_N * sizeof(int), stream);

  // ---- weight planes ----
  k_convT<<<768, 256, 0, stream>>>(n1w1f, w1TH, w1TL, K1, HID);
  k_convT<<<2304, 256, 0, stream>>>(n1w2f, w2TH, w2TL, HID, 1152);
  k_convT<<<1024, 256, 0, stream>>>(simwf, swTH, swTL, HID, HID);
  k_conv<<<1024, 256, 0, stream>>>(simwf, swRH, swRL, HID * HID);  // Ws^T in BT form
  k_convT<<<1024, 256, 0, stream>>>(n2w1f, a2TH, a2TL, HID, HID);
  k_convT<<<256, 256, 0, stream>>>(n2w2f, b2TH, b2TL, HID, 128);

  // ---- CSR of cand_idx ----
  k_count<<<782, 256, 0, stream>>>(edges, cnt);
  k_scan_a<<<49, 1024, 0, stream>>>(cnt, incl, bsum);
  k_scan_b<<<1, 64, 0, stream>>>(bsum, bpre, 49);
  k_scan_c<<<49, 1024, 0, stream>>>(incl, cnt, bpre, excl, cursor);
  k_fill<<<782, 256, 0, stream>>>(edges, cursor, csr);

  // ---- weight folding ----
  {
    dim3 gW(1, 4);
    gemm_k<1, 1, 0, OF_F32><<<gW, 256, 0, stream>>>(
        projwf, nullptr, swTH, swTL, nullptr,
        Wf, nullptr, nullptr, 128, HID, HID, HID, HID, nullptr, nullptr, nullptr, 0);
    gemm_k<1, 1, 0, OF_F32><<<gW, 256, 0, stream>>>(
        Wf, nullptr, swRH, swRL, nullptr,
        Waf, nullptr, nullptr, 128, HID, HID, HID, HID, nullptr, nullptr, nullptr, 0);
    k_convT<<<256, 256, 0, stream>>>(Waf, WaTH, WaTL, 128, HID);
    k_foldb1<<<2, 256, 0, stream>>>(projbf, simwf, simbf, bf1);
    k_foldba<<<2, 256, 0, stream>>>(bf1, simwf, baf);
    k_foldwz<<<1, 256, 0, stream>>>(Wf, simbf, bf1, wzf, bzf);
  }

  // ---- phase B1 (folded): one full-grid gemm obj -> auxhi, plus zs matvec ----
  {
    dim3 gA((O_N + BM - 1) / BM, 4);
    gemm_k<1, 1, 0, OF_HI><<<gA, 256, 0, stream>>>(
        objf, nullptr, WaTH, WaTL, baf,
        nullptr, auxhi, nullptr, O_N, HID, 128, 128, HID, nullptr, nullptr, nullptr, 0);
    k_zsm<<<(O_N + 3) / 4, 256, 0, stream>>>(objf, wzf, bzf, zsb, O_N);
  }

  // ---- phase M: MLP1 + s1 scores, T-chunks ----
  for (int ci = 0; ci < nT; ci++) {
    int r0 = ci * rT;
    int rows = (r0 + rT <= T_N) ? rT : (T_N - r0);
    dim3 g4((rows + BM - 1) / BM, 4);
    dim3 g1((rows + BM - 1) / BM, 1);
    gemm_k<2, 1, 1, OF_HI | OF_LO><<<g4, 256, 0, stream>>>(
        nullptr, nullptr, w1TH, w1TL, n1b1f,
        nullptr, h1H, h1L, rows, HID, K1, 0, HID, edges, objf, predf, r0);
    gemm_k<3, 1, 1, OF_HI | OF_LO><<<g4, 256, 0, stream>>>(
        h1H, h1L, w2TH, w2TL, n1b2f,
        nullptr, newShi + (size_t)r0 * HID, Slo, rows, HID, HID, HID, HID,
        nullptr, nullptr, nullptr, 0);
    gemm_k<3, 1, 1, OF_F32><<<g1, 256, 0, stream>>>(
        h1H, h1L, w2TH + (size_t)512 * HID, w2TL + (size_t)512 * HID, n1b2f + 512,
        out_p + (size_t)r0 * 128, nullptr, nullptr, rows, 128, HID, HID, 128,
        nullptr, nullptr, nullptr, 0);
    gemm_k<3, 1, 1, OF_HI | OF_LO><<<g4, 256, 0, stream>>>(
        h1H, h1L, w2TH + (size_t)640 * HID, w2TL + (size_t)640 * HID, n1b2f + 640,
        nullptr, newOhi + (size_t)r0 * HID, Olo, rows, HID, HID, HID, HID,
        nullptr, nullptr, nullptr, 0);
    k_scores<<<(2 * rows + 3) / 4, 256, 0, stream>>>(
        newShi, newOhi, Slo, Olo, auxhi, zsb, edges, scoresb, r0, rows);
  }

  // ---- score fix: folded fp32 aux per O-chunk (bitwise-matched acc vs auxhi) ----
  for (int ci = 0; ci < nFx; ci++) {
    int q0 = ci * rFx;
    int rows = (q0 + rFx <= O_N) ? rFx : (O_N - q0);
    dim3 g4((rows + BM - 1) / BM, 4);
    gemm_k<1, 1, 0, OF_F32><<<g4, 256, 0, stream>>>(
        objf + (size_t)q0 * 128, nullptr, WaTH, WaTL, baf,
        auxfC, nullptr, nullptr, rows, HID, 128, 128, HID, nullptr, nullptr, nullptr, 0);
    k_fix<<<(rows + 3) / 4, 256, 0, stream>>>(
        newShi, newOhi, auxhi, auxfC, csr, excl, cnt, scoresb, q0, rows);
  }

  // ---- phase C: pool -> MLP2, O-chunks ----
  for (int ci = 0; ci < nOb; ci++) {
    int q0 = ci * rOb;
    int rows = (q0 + rOb <= O_N) ? rOb : (O_N - q0);
    dim3 g4((rows + BM - 1) / BM, 4);
    dim3 g1((rows + BM - 1) / BM, 1);
    k_pool<<<(rows + 3) / 4, 256, 0, stream>>>(
        newShi, newOhi, scoresb, zsb, csr, excl, cnt, pooledf, q0, rows);
    gemm_k<1, 1, 1, OF_HI><<<g4, 256, 0, stream>>>(
        pooledf, nullptr, a2TH, a2TL, n2b1f,
        nullptr, h2c, nullptr, rows, HID, HID, HID, HID, nullptr, nullptr, nullptr, 0);
    gemm_k<0, 1, 1, OF_F32><<<g1, 256, 0, stream>>>(
        h2c, nullptr, b2TH, b2TL, n2b2f,
        out_obj + (size_t)q0 * 128, nullptr, nullptr, rows, 128, HID, HID, 128,
        nullptr, nullptr, nullptr, 0);
  }

  (void)in_sizes; (void)n_in; (void)out_size;
}

// Round 5
// 2012.933 us; speedup vs baseline: 3.0072x; 1.2622x over previous
//
#include <hip/hip_runtime.h>

typedef unsigned short u16;
typedef unsigned int u32;
typedef u16 u16x8 __attribute__((ext_vector_type(8)));
typedef __bf16 bf16x8 __attribute__((ext_vector_type(8)));
typedef float f32x4 __attribute__((ext_vector_type(4)));

#define O_N 50000
#define T_N 100000
#define HID 512
#define K1 384
#define BM 128
#define BN 128
#define BK 32
#define LDT 40  // padded LDS stride (u16); 16B-quad stride 5 (odd) -> conflict-free b128

#define OF_F32 1
#define OF_HI 2
#define OF_LO 4

__device__ __forceinline__ u16 f2bf(float f) {
  u32 u = __float_as_uint(f);
  u += 0x7fffu + ((u >> 16) & 1u);
  return (u16)(u >> 16);
}
__device__ __forceinline__ float bf2f(u16 b) {
  return __uint_as_float(((u32)b) << 16);
}
__device__ __forceinline__ f32x4 mfma16(u16x8 a, u16x8 b, f32x4 c) {
  return __builtin_amdgcn_mfma_f32_16x16x32_bf16(
      __builtin_bit_cast(bf16x8, a), __builtin_bit_cast(bf16x8, b), c, 0, 0, 0);
}
__device__ __forceinline__ float wave_sum(float v) {
#pragma unroll
  for (int m = 32; m >= 1; m >>= 1) v += __shfl_xor(v, m, 64);
  return v;
}

// C[M x N] = act(A @ B + bias_f32). B given as bf16 hi(+lo) planes in BT form [N][K].
// AMODE: 0 = A bf16 (u16*); 1 = A fp32 rows, split in stage; 2 = gathered fp32 t_in
//        rows [obj[s]|pred|obj[o]], split in stage; 3 = A bf16 hi/lo planes.
// BSPLIT: stage B lo plane, add Ah*Bl term. Split: acc = Ah*Bh (+ Al*Bh) (+ Ah*Bl).
// FUSE: M-phase fused epilogue over N=1152: cols 0-511 -> Ch/Cl (ldc 512),
//       512-639 -> Cf fp32 (ldc 128), 640-1151 -> Ch2/Cl2 (ldc 512). All ReLU.
template <int AMODE, int BSPLIT, int RELU, int OFLAGS, int FUSE>
__global__ __launch_bounds__(256) void gemm_k(
    const void* __restrict__ Ap, const u16* __restrict__ Apl,
    const u16* __restrict__ Bph, const u16* __restrict__ Bpl,
    const float* __restrict__ biasf,
    float* __restrict__ Cf, u16* __restrict__ Ch, u16* __restrict__ Cl,
    u16* __restrict__ Ch2, u16* __restrict__ Cl2,
    int M, int N, int K, int lda, int ldc,
    const int* __restrict__ edges, const float* __restrict__ objf,
    const float* __restrict__ predf, int r0) {
  const bool ASPLIT = (AMODE == 1 || AMODE == 2 || AMODE == 3);
  __shared__ u16 Ah[BM * LDT];
  __shared__ u16 Al[(AMODE == 1 || AMODE == 2 || AMODE == 3) ? BM * LDT : 8];
  __shared__ u16 Bh[BN * LDT];
  __shared__ u16 Bl[BSPLIT ? BN * LDT : 8];

  const int tid = threadIdx.x;
  const int lane = tid & 63;
  const int wave = tid >> 6;
  const int wm = (wave >> 1) * 64;
  const int wn = (wave & 1) * 64;
  const int m0 = blockIdx.x * BM;
  const int n0 = blockIdx.y * BN;
  const int sr = tid >> 1;        // staged tile row
  const int sh = (tid & 1) * 16;  // k-offset half

  f32x4 acc[4][4] = {};

  for (int k0 = 0; k0 < K; k0 += BK) {
    __syncthreads();
    // ---- stage A ----
    if (AMODE == 0) {
      u16x8 v0 = {0, 0, 0, 0, 0, 0, 0, 0}, v1 = {0, 0, 0, 0, 0, 0, 0, 0};
      if (m0 + sr < M) {
        const u16* src = (const u16*)Ap + (size_t)(m0 + sr) * lda + k0 + sh;
        v0 = *(const u16x8*)src;
        v1 = *(const u16x8*)(src + 8);
      }
      *(u16x8*)&Ah[sr * LDT + sh] = v0;
      *(u16x8*)&Ah[sr * LDT + sh + 8] = v1;
    } else if (AMODE == 3) {
      u16x8 h0 = {0, 0, 0, 0, 0, 0, 0, 0}, h1 = h0, l0 = h0, l1 = h0;
      if (m0 + sr < M) {
        size_t base = (size_t)(m0 + sr) * lda + k0 + sh;
        h0 = *(const u16x8*)((const u16*)Ap + base);
        h1 = *(const u16x8*)((const u16*)Ap + base + 8);
        l0 = *(const u16x8*)(Apl + base);
        l1 = *(const u16x8*)(Apl + base + 8);
      }
      *(u16x8*)&Ah[sr * LDT + sh] = h0;
      *(u16x8*)&Ah[sr * LDT + sh + 8] = h1;
      *(u16x8*)&Al[sr * LDT + sh] = l0;
      *(u16x8*)&Al[sr * LDT + sh + 8] = l1;
    } else {  // AMODE 1 or 2: fp32 source, split into hi/lo
      float vals[16];
      if (m0 + sr < M) {
        const float* src;
        if (AMODE == 1) {
          src = (const float*)Ap + (size_t)(m0 + sr) * lda + k0 + sh;
        } else {
          int gr = r0 + m0 + sr;
          int col = k0 + sh;  // 16-col segment inside one source (128|128|128)
          if (col < 128) src = objf + (size_t)edges[gr * 2] * 128 + col;
          else if (col < 256) src = predf + (size_t)gr * 128 + (col - 128);
          else src = objf + (size_t)edges[gr * 2 + 1] * 128 + (col - 256);
        }
        const f32x4* s4 = (const f32x4*)src;
        f32x4 a0 = s4[0], a1 = s4[1], a2 = s4[2], a3 = s4[3];
#pragma unroll
        for (int i = 0; i < 4; i++) {
          vals[i] = a0[i]; vals[4 + i] = a1[i]; vals[8 + i] = a2[i]; vals[12 + i] = a3[i];
        }
      } else {
#pragma unroll
        for (int i = 0; i < 16; i++) vals[i] = 0.f;
      }
      u16x8 h0, h1, l0, l1;
#pragma unroll
      for (int i = 0; i < 8; i++) {
        u16 hb = f2bf(vals[i]);
        h0[i] = hb; l0[i] = f2bf(vals[i] - bf2f(hb));
        u16 hb2 = f2bf(vals[8 + i]);
        h1[i] = hb2; l1[i] = f2bf(vals[8 + i] - bf2f(hb2));
      }
      *(u16x8*)&Ah[sr * LDT + sh] = h0;
      *(u16x8*)&Ah[sr * LDT + sh + 8] = h1;
      *(u16x8*)&Al[sr * LDT + sh] = l0;
      *(u16x8*)&Al[sr * LDT + sh + 8] = l1;
    }
    // ---- stage B ----
    {
      size_t base = (size_t)(n0 + sr) * K + k0 + sh;
      u16x8 b0 = *(const u16x8*)(Bph + base);
      u16x8 b1 = *(const u16x8*)(Bph + base + 8);
      *(u16x8*)&Bh[sr * LDT + sh] = b0;
      *(u16x8*)&Bh[sr * LDT + sh + 8] = b1;
      if (BSPLIT) {
        u16x8 c0 = *(const u16x8*)(Bpl + base);
        u16x8 c1 = *(const u16x8*)(Bpl + base + 8);
        *(u16x8*)&Bl[sr * LDT + sh] = c0;
        *(u16x8*)&Bl[sr * LDT + sh + 8] = c1;
      }
    }
    __syncthreads();
    // ---- fragments + MFMA ----
    const int fr = lane & 15;
    const int q8 = (lane >> 4) * 8;
    u16x8 af[4], bf[4];
#pragma unroll
    for (int i = 0; i < 4; i++) af[i] = *(const u16x8*)&Ah[(wm + i * 16 + fr) * LDT + q8];
#pragma unroll
    for (int j = 0; j < 4; j++) bf[j] = *(const u16x8*)&Bh[(wn + j * 16 + fr) * LDT + q8];
#pragma unroll
    for (int i = 0; i < 4; i++)
#pragma unroll
      for (int j = 0; j < 4; j++) acc[i][j] = mfma16(af[i], bf[j], acc[i][j]);
    if (ASPLIT) {
      u16x8 alf[4];
#pragma unroll
      for (int i = 0; i < 4; i++) alf[i] = *(const u16x8*)&Al[(wm + i * 16 + fr) * LDT + q8];
#pragma unroll
      for (int i = 0; i < 4; i++)
#pragma unroll
        for (int j = 0; j < 4; j++) acc[i][j] = mfma16(alf[i], bf[j], acc[i][j]);
    }
    if (BSPLIT) {
      u16x8 blf[4];
#pragma unroll
      for (int j = 0; j < 4; j++) blf[j] = *(const u16x8*)&Bl[(wn + j * 16 + fr) * LDT + q8];
#pragma unroll
      for (int i = 0; i < 4; i++)
#pragma unroll
        for (int j = 0; j < 4; j++) acc[i][j] = mfma16(af[i], blf[j], acc[i][j]);
    }
  }
  // ---- epilogue: C/D layout col=lane&15, row=(lane>>4)*4+reg (m89/m91 verified) ----
  const int fc = lane & 15;
  const int fr4 = (lane >> 4) * 4;
#pragma unroll
  for (int j = 0; j < 4; j++) {
    int col = n0 + wn + j * 16 + fc;
    float bv = biasf ? biasf[col] : 0.f;
#pragma unroll
    for (int i = 0; i < 4; i++) {
      int rbase = m0 + wm + i * 16 + fr4;
#pragma unroll
      for (int rr = 0; rr < 4; rr++) {
        int row = rbase + rr;
        if (row < M) {
          float v = acc[i][j][rr] + bv;
          if (RELU) v = fmaxf(v, 0.f);
          if (FUSE) {
            if (col < 512) {
              size_t ci = (size_t)row * 512 + col;
              u16 h = f2bf(v);
              Ch[ci] = h;
              Cl[ci] = f2bf(v - bf2f(h));
            } else if (col < 640) {
              Cf[(size_t)row * 128 + (col - 512)] = v;
            } else {
              size_t ci = (size_t)row * 512 + (col - 640);
              u16 h = f2bf(v);
              Ch2[ci] = h;
              Cl2[ci] = f2bf(v - bf2f(h));
            }
          } else {
            size_t ci = (size_t)row * ldc + col;
            if (OFLAGS & OF_F32) Cf[ci] = v;
            if (OFLAGS & OF_HI) {
              u16 h = f2bf(v);
              Ch[ci] = h;
              if (OFLAGS & OF_LO) Cl[ci] = f2bf(v - bf2f(h));
            }
          }
        }
      }
    }
  }
}

// fp32 [K][N] -> bf16 hi(+lo) planes in BT form [N][K]. outl may be null.
__global__ void k_convT(const float* __restrict__ in, u16* __restrict__ outh,
                        u16* __restrict__ outl, int K, int N) {
  int idx = blockIdx.x * 256 + threadIdx.x;
  if (idx >= K * N) return;
  int n = idx / K, k = idx % K;
  float v = in[(size_t)k * N + n];
  u16 h = f2bf(v);
  outh[idx] = h;
  if (outl) outl[idx] = f2bf(v - bf2f(h));
}

// fp32 -> bf16 hi/lo planes, elementwise
__global__ void k_conv(const float* __restrict__ in, u16* __restrict__ outh,
                       u16* __restrict__ outl, int n) {
  int idx = blockIdx.x * 256 + threadIdx.x;
  if (idx >= n) return;
  float v = in[idx];
  u16 h = f2bf(v);
  outh[idx] = h;
  if (outl) outl[idx] = f2bf(v - bf2f(h));
}

// ---- weight folding (all fp32, trivial FLOPs) ----
// bf1[n] = sum_k bp[k]*Ws[k][n] + bs[n]
__global__ void k_foldb1(const float* __restrict__ bp, const float* __restrict__ Ws,
                         const float* __restrict__ bs, float* __restrict__ bf1) {
  int n = blockIdx.x * 256 + threadIdx.x;
  if (n >= HID) return;
  float s = bs[n];
  for (int k = 0; k < HID; k++) s += bp[k] * Ws[(size_t)k * HID + n];
  bf1[n] = s;
}
// ba[n] = sum_k bf1[k]*Ws[n][k]   (row n of Ws)
__global__ void k_foldba(const float* __restrict__ bf1, const float* __restrict__ Ws,
                         float* __restrict__ ba) {
  int n = blockIdx.x * 256 + threadIdx.x;
  if (n >= HID) return;
  float s = 0.f;
  for (int k = 0; k < HID; k++) s += bf1[k] * Ws[(size_t)n * HID + k];
  ba[n] = s;
}
// wz[m] = sum_n Wf[m][n]*bs[n];  bz = bf1.bs
__global__ void k_foldwz(const float* __restrict__ Wf, const float* __restrict__ bs,
                         const float* __restrict__ bf1, float* __restrict__ wz,
                         float* __restrict__ bz) {
  int m = blockIdx.x * 256 + threadIdx.x;
  if (m < 128) {
    float s = 0.f;
    for (int n = 0; n < HID; n++) s += Wf[(size_t)m * HID + n] * bs[n];
    wz[m] = s;
  }
  if (m == 128) {
    float s = 0.f;
    for (int n = 0; n < HID; n++) s += bf1[n] * bs[n];
    *bz = s;
  }
}
// zs[o] = obj[o].wz + bz   (replaces pp.bs via folding)
__global__ void k_zsm(const float* __restrict__ obj, const float* __restrict__ wz,
                      const float* __restrict__ bz, float* __restrict__ zs, int rows) {
  int o = blockIdx.x * 4 + (threadIdx.x >> 6);
  int lane = threadIdx.x & 63;
  if (o >= rows) return;
  const float2* row = (const float2*)(obj + (size_t)o * 128);
  float2 v = row[lane];
  float2 w = ((const float2*)wz)[lane];
  float d = v.x * w.x + v.y * w.y;
  d = wave_sum(d);
  if (lane == 0) zs[o] = d + *bz;
}

__global__ void k_count(const int* __restrict__ edges, int* __restrict__ cnt) {
  int e = blockIdx.x * 256 + threadIdx.x;
  if (e >= 2 * T_N) return;
  int c = (e < T_N) ? edges[e * 2 + 0] : edges[(e - T_N) * 2 + 1];
  atomicAdd(cnt + c, 1);
}

__global__ void k_scan_a(const int* __restrict__ cnt, int* __restrict__ incl,
                         int* __restrict__ bsum) {
  __shared__ int sb[1024];
  int i = blockIdx.x * 1024 + threadIdx.x;
  int v = (i < O_N) ? cnt[i] : 0;
  sb[threadIdx.x] = v;
  __syncthreads();
  for (int ofs = 1; ofs < 1024; ofs <<= 1) {
    int t = (threadIdx.x >= ofs) ? sb[threadIdx.x - ofs] : 0;
    __syncthreads();
    sb[threadIdx.x] += t;
    __syncthreads();
  }
  if (i < O_N) incl[i] = sb[threadIdx.x];
  if (threadIdx.x == 1023) bsum[blockIdx.x] = sb[1023];
}

__global__ void k_scan_b(const int* __restrict__ bsum, int* __restrict__ bpre, int nb) {
  if (threadIdx.x == 0 && blockIdx.x == 0) {
    int run = 0;
    for (int b = 0; b < nb; b++) { bpre[b] = run; run += bsum[b]; }
  }
}

__global__ void k_scan_c(const int* __restrict__ incl, const int* __restrict__ cnt,
                         const int* __restrict__ bpre, int* __restrict__ excl,
                         int* __restrict__ cursor) {
  int i = blockIdx.x * 1024 + threadIdx.x;
  if (i >= O_N) return;
  int ex = incl[i] - cnt[i] + bpre[blockIdx.x];
  excl[i] = ex;
  cursor[i] = ex;
}

__global__ void k_fill(const int* __restrict__ edges, int* __restrict__ cursor,
                       int* __restrict__ csr) {
  int e = blockIdx.x * 256 + threadIdx.x;
  if (e >= 2 * T_N) return;
  int c = (e < T_N) ? edges[e * 2 + 0] : edges[(e - T_N) * 2 + 1];
  int pos = atomicAdd(cursor + c, 1);
  csr[pos] = e;
}

// phase M scores: s1 = (cand_hi + cand_lo) . aux_hi + zs[c]  (corrected by k_fix)
__global__ void k_scores(const u16* __restrict__ newShi, const u16* __restrict__ newOhi,
                         const u16* __restrict__ Slo, const u16* __restrict__ Olo,
                         const u16* __restrict__ auxhi, const float* __restrict__ zs,
                         const int* __restrict__ edges, float* __restrict__ scores,
                         int r0, int rows) {
  int idx = blockIdx.x * 4 + (threadIdx.x >> 6);
  int lane = threadIdx.x & 63;
  int rl = idx >> 1, side = idx & 1;
  if (rl >= rows) return;
  int grow = r0 + rl;
  int c = edges[grow * 2 + side];
  u16x8 ch = *(const u16x8*)((side ? newOhi : newShi) + (size_t)grow * HID + lane * 8);
  u16x8 cl = *(const u16x8*)((side ? Olo : Slo) + (size_t)rl * HID + lane * 8);
  u16x8 ah = *(const u16x8*)(auxhi + (size_t)c * HID + lane * 8);
  float d = 0.f;
#pragma unroll
  for (int k = 0; k < 8; k++) d += (bf2f(ch[k]) + bf2f(cl[k])) * bf2f(ah[k]);
  d = wave_sum(d);
  if (lane == 0) scores[(side ? T_N : 0) + grow] = d + zs[c];
}

// score fix: scores[e] += cand_hi . (auxf - auxhi), per O-chunk
__global__ void k_fix(const u16* __restrict__ newShi, const u16* __restrict__ newOhi,
                      const u16* __restrict__ auxhi, const float* __restrict__ auxf,
                      const int* __restrict__ csr, const int* __restrict__ excl,
                      const int* __restrict__ cnt, float* __restrict__ scores,
                      int q0, int rows) {
  int ol = blockIdx.x * 4 + (threadIdx.x >> 6);
  int lane = threadIdx.x & 63;
  if (ol >= rows) return;
  int o = q0 + ol;
  int off = excl[o], deg = cnt[o];
  if (deg == 0) return;
  const f32x4* afp = (const f32x4*)(auxf + (size_t)ol * HID + lane * 8);
  f32x4 af0 = afp[0], af1 = afp[1];
  u16x8 ah = *(const u16x8*)(auxhi + (size_t)o * HID + lane * 8);
  float al[8];
#pragma unroll
  for (int k = 0; k < 4; k++) {
    al[k] = af0[k] - bf2f(ah[k]);
    al[4 + k] = af1[k] - bf2f(ah[4 + k]);
  }
  for (int i = 0; i < deg; i++) {
    int e = csr[off + i];
    const u16* cand =
        (e < T_N) ? newShi + (size_t)e * HID : newOhi + (size_t)(e - T_N) * HID;
    u16x8 ch = *(const u16x8*)(cand + lane * 8);
    float d = 0.f;
#pragma unroll
    for (int k = 0; k < 8; k++) d += bf2f(ch[k]) * al[k];
    d = wave_sum(d);
    if (lane == 0) scores[e] += d;  // each edge owned by exactly one object: no race
  }
}

__global__ void k_pool(const u16* __restrict__ newShi, const u16* __restrict__ newOhi,
                       const float* __restrict__ scores, const float* __restrict__ zs,
                       const int* __restrict__ csr, const int* __restrict__ excl,
                       const int* __restrict__ cnt, float* __restrict__ pooledf,
                       int q0, int rows) {
  int ol = blockIdx.x * 4 + (threadIdx.x >> 6);
  int lane = threadIdx.x & 63;
  if (ol >= rows) return;
  int o = q0 + ol;
  int off = excl[o], deg = cnt[o];
  float zso = zs[o];
  float m = zso;
  for (int base = 0; base < deg; base += 64) {
    float s = (base + lane < deg) ? scores[csr[off + base + lane]] : -3.4e38f;
    m = fmaxf(m, s);
  }
#pragma unroll
  for (int x = 32; x >= 1; x >>= 1) m = fmaxf(m, __shfl_xor(m, x, 64));
  float denom = __expf(zso - m);
  float acc[8] = {0, 0, 0, 0, 0, 0, 0, 0};
  for (int i = 0; i < deg; i++) {
    int e = csr[off + i];
    float w = __expf(scores[e] - m);
    denom += w;
    const u16* cand =
        (e < T_N) ? newShi + (size_t)e * HID : newOhi + (size_t)(e - T_N) * HID;
    u16x8 cv = *(const u16x8*)(cand + lane * 8);
#pragma unroll
    for (int k = 0; k < 8; k++) acc[k] += w * bf2f(cv[k]);
  }
  float inv = 1.0f / denom;
  f32x4 o0, o1;
#pragma unroll
  for (int k = 0; k < 4; k++) {
    o0[k] = acc[k] * inv;
    o1[k] = acc[4 + k] * inv;
  }
  f32x4* dst = (f32x4*)(pooledf + (size_t)ol * HID + lane * 8);
  dst[0] = o0;
  dst[1] = o1;
}

extern "C" void kernel_launch(void* const* d_in, const int* in_sizes, int n_in,
                              void* d_out, int out_size, void* d_ws, size_t ws_size,
                              hipStream_t stream) {
  const float* objf = (const float*)d_in[0];
  const float* predf = (const float*)d_in[1];
  const int* edges = (const int*)d_in[2];
  const float* n1w1f = (const float*)d_in[3];
  const float* n1b1f = (const float*)d_in[4];
  const float* n1w2f = (const float*)d_in[5];
  const float* n1b2f = (const float*)d_in[6];
  const float* n2w1f = (const float*)d_in[7];
  const float* n2b1f = (const float*)d_in[8];
  const float* n2w2f = (const float*)d_in[9];
  const float* n2b2f = (const float*)d_in[10];
  const float* projwf = (const float*)d_in[11];
  const float* projbf = (const float*)d_in[12];
  const float* simwf = (const float*)d_in[13];
  const float* simbf = (const float*)d_in[14];

  float* out_obj = (float*)d_out;                    // O x 128 fp32
  float* out_p = (float*)d_out + (size_t)O_N * 128;  // T x 128 fp32

  // ---- weight-folded scheme + fused M-phase gemm ----
  const long long FIXED = 267000000ll;
  long long budget = (long long)ws_size - FIXED;
  if (budget < 5000000ll) budget = 5000000ll;
  long long rT_l = budget / 4096;  if (rT_l > 26000) rT_l = 26000;
  int rT = (int)(rT_l & ~127ll);   if (rT < 1280) rT = 1280;
  long long rOb_l = budget / 3072; if (rOb_l > 25000) rOb_l = 25000;
  int rOb = (int)rOb_l;            if (rOb < 1280) rOb = 1280;
  long long rFx_l = budget / 2048; if (rFx_l > 25000) rFx_l = 25000;
  int rFx = (int)rFx_l;            if (rFx < 1280) rFx = 1280;
  const int nT = (T_N + rT - 1) / rT;
  const int nOb = (O_N + rOb - 1) / rOb;
  const int nFx = (O_N + rFx - 1) / rFx;
  size_t arena_sz = (size_t)rT * 4096;
  if ((size_t)rOb * 3072 > arena_sz) arena_sz = (size_t)rOb * 3072;
  if ((size_t)rFx * 2048 > arena_sz) arena_sz = (size_t)rFx * 2048;
  arena_sz = (arena_sz + 4095) & ~(size_t)4095;

  char* ws = (char*)d_ws;
  size_t off = 0;
  u16* newShi = (u16*)(ws + off); off += (size_t)T_N * HID * 2;  // 102.4 MB
  u16* newOhi = (u16*)(ws + off); off += (size_t)T_N * HID * 2;  // 102.4 MB
  u16* auxhi = (u16*)(ws + off);  off += (size_t)O_N * HID * 2;  // 51.2 MB
  char* arena = ws + off; off += arena_sz;

  // phase M views
  u16* h1H = (u16*)arena;
  u16* h1L = (u16*)(arena + (size_t)rT * HID * 2);
  u16* Slo = (u16*)(arena + (size_t)rT * HID * 4);
  u16* Olo = (u16*)(arena + (size_t)rT * HID * 6);
  // fix-phase view
  float* auxfC = (float*)arena;
  // phase C views
  float* pooledf = (float*)arena;
  u16* h2c = (u16*)(arena + (size_t)rOb * HID * 4);

  float* scoresb = (float*)(ws + off); off += (size_t)2 * T_N * 4;
  float* zsb = (float*)(ws + off); off += (size_t)O_N * 4;
  int* cnt = (int*)(ws + off); off += (size_t)O_N * 4;
  int* incl = (int*)(ws + off); off += (size_t)O_N * 4;
  int* excl = (int*)(ws + off); off += (size_t)O_N * 4;
  int* cursor = (int*)(ws + off); off += (size_t)O_N * 4;
  int* csr = (int*)(ws + off); off += (size_t)2 * T_N * 4;
  int* bsum = (int*)(ws + off); off += 4096;
  int* bpre = (int*)(ws + off); off += 4096;
  u16* w1TH = (u16*)(ws + off); off += (size_t)K1 * HID * 2;
  u16* w1TL = (u16*)(ws + off); off += (size_t)K1 * HID * 2;
  u16* w2TH = (u16*)(ws + off); off += (size_t)1152 * HID * 2;
  u16* w2TL = (u16*)(ws + off); off += (size_t)1152 * HID * 2;
  u16* swTH = (u16*)(ws + off); off += (size_t)HID * HID * 2;
  u16* swTL = (u16*)(ws + off); off += (size_t)HID * HID * 2;
  u16* swRH = (u16*)(ws + off); off += (size_t)HID * HID * 2;
  u16* swRL = (u16*)(ws + off); off += (size_t)HID * HID * 2;
  u16* a2TH = (u16*)(ws + off); off += (size_t)HID * HID * 2;
  u16* a2TL = (u16*)(ws + off); off += (size_t)HID * HID * 2;
  u16* b2TH = (u16*)(ws + off); off += (size_t)128 * HID * 2;
  u16* b2TL = (u16*)(ws + off); off += (size_t)128 * HID * 2;
  float* Wf = (float*)(ws + off);  off += (size_t)128 * HID * 4;  // Wp@Ws
  float* Waf = (float*)(ws + off); off += (size_t)128 * HID * 4;  // Wf@Ws^T
  u16* WaTH = (u16*)(ws + off); off += (size_t)HID * 128 * 2;
  u16* WaTL = (u16*)(ws + off); off += (size_t)HID * 128 * 2;
  float* bf1 = (float*)(ws + off); off += 2048;
  float* baf = (float*)(ws + off); off += 2048;
  float* wzf = (float*)(ws + off); off += 512;
  float* bzf = (float*)(ws + off); off += 16;

  hipMemsetAsync(cnt, 0, O_N * sizeof(int), stream);

  // ---- weight planes ----
  k_convT<<<768, 256, 0, stream>>>(n1w1f, w1TH, w1TL, K1, HID);
  k_convT<<<2304, 256, 0, stream>>>(n1w2f, w2TH, w2TL, HID, 1152);
  k_convT<<<1024, 256, 0, stream>>>(simwf, swTH, swTL, HID, HID);
  k_conv<<<1024, 256, 0, stream>>>(simwf, swRH, swRL, HID * HID);  // Ws^T in BT form
  k_convT<<<1024, 256, 0, stream>>>(n2w1f, a2TH, a2TL, HID, HID);
  k_convT<<<256, 256, 0, stream>>>(n2w2f, b2TH, b2TL, HID, 128);

  // ---- CSR of cand_idx ----
  k_count<<<782, 256, 0, stream>>>(edges, cnt);
  k_scan_a<<<49, 1024, 0, stream>>>(cnt, incl, bsum);
  k_scan_b<<<1, 64, 0, stream>>>(bsum, bpre, 49);
  k_scan_c<<<49, 1024, 0, stream>>>(incl, cnt, bpre, excl, cursor);
  k_fill<<<782, 256, 0, stream>>>(edges, cursor, csr);

  // ---- weight folding ----
  {
    dim3 gW(1, 4);
    gemm_k<1, 1, 0, OF_F32, 0><<<gW, 256, 0, stream>>>(
        projwf, nullptr, swTH, swTL, nullptr,
        Wf, nullptr, nullptr, nullptr, nullptr,
        128, HID, HID, HID, HID, nullptr, nullptr, nullptr, 0);
    gemm_k<1, 1, 0, OF_F32, 0><<<gW, 256, 0, stream>>>(
        Wf, nullptr, swRH, swRL, nullptr,
        Waf, nullptr, nullptr, nullptr, nullptr,
        128, HID, HID, HID, HID, nullptr, nullptr, nullptr, 0);
    k_convT<<<256, 256, 0, stream>>>(Waf, WaTH, WaTL, 128, HID);
    k_foldb1<<<2, 256, 0, stream>>>(projbf, simwf, simbf, bf1);
    k_foldba<<<2, 256, 0, stream>>>(bf1, simwf, baf);
    k_foldwz<<<1, 256, 0, stream>>>(Wf, simbf, bf1, wzf, bzf);
  }

  // ---- phase B1 (folded): one full-grid gemm obj -> auxhi, plus zs matvec ----
  {
    dim3 gA((O_N + BM - 1) / BM, 4);
    gemm_k<1, 1, 0, OF_HI, 0><<<gA, 256, 0, stream>>>(
        objf, nullptr, WaTH, WaTL, baf,
        nullptr, auxhi, nullptr, nullptr, nullptr,
        O_N, HID, 128, 128, HID, nullptr, nullptr, nullptr, 0);
    k_zsm<<<(O_N + 3) / 4, 256, 0, stream>>>(objf, wzf, bzf, zsb, O_N);
  }

  // ---- phase M: MLP1 (gather gemm) + fused N=1152 gemm + scores, T-chunks ----
  for (int ci = 0; ci < nT; ci++) {
    int r0 = ci * rT;
    int rows = (r0 + rT <= T_N) ? rT : (T_N - r0);
    dim3 g4((rows + BM - 1) / BM, 4);
    dim3 g9((rows + BM - 1) / BM, 9);
    gemm_k<2, 1, 1, OF_HI | OF_LO, 0><<<g4, 256, 0, stream>>>(
        nullptr, nullptr, w1TH, w1TL, n1b1f,
        nullptr, h1H, h1L, nullptr, nullptr,
        rows, HID, K1, 0, HID, edges, objf, predf, r0);
    // fused: cols 0-511 -> newShi+Slo, 512-639 -> out_p, 640-1151 -> newOhi+Olo
    gemm_k<3, 1, 1, 0, 1><<<g9, 256, 0, stream>>>(
        h1H, h1L, w2TH, w2TL, n1b2f,
        out_p + (size_t)r0 * 128, newShi + (size_t)r0 * HID, Slo,
        newOhi + (size_t)r0 * HID, Olo,
        rows, 1152, HID, HID, HID, nullptr, nullptr, nullptr, 0);
    k_scores<<<(2 * rows + 3) / 4, 256, 0, stream>>>(
        newShi, newOhi, Slo, Olo, auxhi, zsb, edges, scoresb, r0, rows);
  }

  // ---- score fix: folded fp32 aux per O-chunk ----
  for (int ci = 0; ci < nFx; ci++) {
    int q0 = ci * rFx;
    int rows = (q0 + rFx <= O_N) ? rFx : (O_N - q0);
    dim3 g4((rows + BM - 1) / BM, 4);
    gemm_k<1, 1, 0, OF_F32, 0><<<g4, 256, 0, stream>>>(
        objf + (size_t)q0 * 128, nullptr, WaTH, WaTL, baf,
        auxfC, nullptr, nullptr, nullptr, nullptr,
        rows, HID, 128, 128, HID, nullptr, nullptr, nullptr, 0);
    k_fix<<<(rows + 3) / 4, 256, 0, stream>>>(
        newShi, newOhi, auxhi, auxfC, csr, excl, cnt, scoresb, q0, rows);
  }

  // ---- phase C: pool -> MLP2, O-chunks ----
  for (int ci = 0; ci < nOb; ci++) {
    int q0 = ci * rOb;
    int rows = (q0 + rOb <= O_N) ? rOb : (O_N - q0);
    dim3 g4((rows + BM - 1) / BM, 4);
    dim3 g1((rows + BM - 1) / BM, 1);
    k_pool<<<(rows + 3) / 4, 256, 0, stream>>>(
        newShi, newOhi, scoresb, zsb, csr, excl, cnt, pooledf, q0, rows);
    gemm_k<1, 1, 1, OF_HI, 0><<<g4, 256, 0, stream>>>(
        pooledf, nullptr, a2TH, a2TL, n2b1f,
        nullptr, h2c, nullptr, nullptr, nullptr,
        rows, HID, HID, HID, HID, nullptr, nullptr, nullptr, 0);
    gemm_k<0, 1, 1, OF_F32, 0><<<g1, 256, 0, stream>>>(
        h2c, nullptr, b2TH, b2TL, n2b2f,
        out_obj + (size_t)q0 * 128, nullptr, nullptr, nullptr, nullptr,
        rows, 128, HID, HID, 128, nullptr, nullptr, nullptr, 0);
  }

  (void)in_sizes; (void)n_in; (void)out_size;
}

// Round 7
// 1905.324 us; speedup vs baseline: 3.1771x; 1.0565x over previous
//
#include <hip/hip_runtime.h>

typedef unsigned short u16;
typedef unsigned int u32;
typedef u16 u16x8 __attribute__((ext_vector_type(8)));
typedef __bf16 bf16x8 __attribute__((ext_vector_type(8)));
typedef float f32x4 __attribute__((ext_vector_type(4)));

#define O_N 50000
#define T_N 100000
#define HID 512
#define K1 384
#define BM 128
#define BN 128
#define BK 32
#define LDT 40  // padded LDS stride (u16); 16B-quad stride 5 (odd) -> conflict-free b128

#define OF_F32 1
#define OF_HI 2
#define OF_LO 4

__device__ __forceinline__ u16 f2bf(float f) {
  u32 u = __float_as_uint(f);
  u += 0x7fffu + ((u >> 16) & 1u);
  return (u16)(u >> 16);
}
__device__ __forceinline__ float bf2f(u16 b) {
  return __uint_as_float(((u32)b) << 16);
}
__device__ __forceinline__ f32x4 mfma16(u16x8 a, u16x8 b, f32x4 c) {
  return __builtin_amdgcn_mfma_f32_16x16x32_bf16(
      __builtin_bit_cast(bf16x8, a), __builtin_bit_cast(bf16x8, b), c, 0, 0, 0);
}
__device__ __forceinline__ float wave_sum(float v) {
#pragma unroll
  for (int m = 32; m >= 1; m >>= 1) v += __shfl_xor(v, m, 64);
  return v;
}

// C[M x N] = act(A @ B + bias_f32). B given as bf16 hi(+lo) planes in BT form [N][K].
// AMODE: 0 = A bf16; 1 = A fp32 rows, split in stage; 2 = gathered fp32 t_in rows;
//        3 = A bf16 hi/lo planes.
// BSPLIT: stage B lo plane, add Ah*Bl term.
// FUSE: M-phase epilogue over N=1152: cols 0-511 -> Ch (newShi), 512-639 -> Cf fp32
//       (out_p), 640-1151 -> Ch2 (newOhi); all ReLU; per-row score partials
//       sum(v * aux[edge]) reduced in-block and atomicAdd'ed into scoresp.
template <int AMODE, int BSPLIT, int RELU, int OFLAGS, int FUSE>
__global__ __launch_bounds__(256) void gemm_k(
    const void* __restrict__ Ap, const u16* __restrict__ Apl,
    const u16* __restrict__ Bph, const u16* __restrict__ Bpl,
    const float* __restrict__ biasf,
    float* __restrict__ Cf, u16* __restrict__ Ch, u16* __restrict__ Cl,
    u16* __restrict__ Ch2,
    int M, int N, int K, int lda, int ldc,
    const int* __restrict__ edges, const float* __restrict__ objf,
    const float* __restrict__ predf, int r0,
    const u16* __restrict__ auxp, float* __restrict__ scoresp) {
  const bool ASPLIT = (AMODE == 1 || AMODE == 2 || AMODE == 3);
  __shared__ u16 Ah[BM * LDT];
  __shared__ u16 Al[(AMODE == 1 || AMODE == 2 || AMODE == 3) ? BM * LDT : 8];
  __shared__ u16 Bh[BN * LDT];
  __shared__ u16 Bl[BSPLIT ? BN * LDT : 8];

  const int tid = threadIdx.x;
  const int lane = tid & 63;
  const int wave = tid >> 6;
  const int wm = (wave >> 1) * 64;
  const int wn = (wave & 1) * 64;
  const int m0 = blockIdx.x * BM;
  const int n0 = blockIdx.y * BN;
  const int sr = tid >> 1;        // staged tile row
  const int sh = (tid & 1) * 16;  // k-offset half

  f32x4 acc[4][4] = {};

  for (int k0 = 0; k0 < K; k0 += BK) {
    __syncthreads();
    // ---- stage A ----
    if (AMODE == 0) {
      u16x8 v0 = {0, 0, 0, 0, 0, 0, 0, 0}, v1 = {0, 0, 0, 0, 0, 0, 0, 0};
      if (m0 + sr < M) {
        const u16* src = (const u16*)Ap + (size_t)(m0 + sr) * lda + k0 + sh;
        v0 = *(const u16x8*)src;
        v1 = *(const u16x8*)(src + 8);
      }
      *(u16x8*)&Ah[sr * LDT + sh] = v0;
      *(u16x8*)&Ah[sr * LDT + sh + 8] = v1;
    } else if (AMODE == 3) {
      u16x8 h0 = {0, 0, 0, 0, 0, 0, 0, 0}, h1 = h0, l0 = h0, l1 = h0;
      if (m0 + sr < M) {
        size_t base = (size_t)(m0 + sr) * lda + k0 + sh;
        h0 = *(const u16x8*)((const u16*)Ap + base);
        h1 = *(const u16x8*)((const u16*)Ap + base + 8);
        l0 = *(const u16x8*)(Apl + base);
        l1 = *(const u16x8*)(Apl + base + 8);
      }
      *(u16x8*)&Ah[sr * LDT + sh] = h0;
      *(u16x8*)&Ah[sr * LDT + sh + 8] = h1;
      *(u16x8*)&Al[sr * LDT + sh] = l0;
      *(u16x8*)&Al[sr * LDT + sh + 8] = l1;
    } else {  // AMODE 1 or 2: fp32 source, split into hi/lo
      float vals[16];
      if (m0 + sr < M) {
        const float* src;
        if (AMODE == 1) {
          src = (const float*)Ap + (size_t)(m0 + sr) * lda + k0 + sh;
        } else {
          int gr = r0 + m0 + sr;
          int col = k0 + sh;  // 16-col segment inside one source (128|128|128)
          if (col < 128) src = objf + (size_t)edges[gr * 2] * 128 + col;
          else if (col < 256) src = predf + (size_t)gr * 128 + (col - 128);
          else src = objf + (size_t)edges[gr * 2 + 1] * 128 + (col - 256);
        }
        const f32x4* s4 = (const f32x4*)src;
        f32x4 a0 = s4[0], a1 = s4[1], a2 = s4[2], a3 = s4[3];
#pragma unroll
        for (int i = 0; i < 4; i++) {
          vals[i] = a0[i]; vals[4 + i] = a1[i]; vals[8 + i] = a2[i]; vals[12 + i] = a3[i];
        }
      } else {
#pragma unroll
        for (int i = 0; i < 16; i++) vals[i] = 0.f;
      }
      u16x8 h0, h1, l0, l1;
#pragma unroll
      for (int i = 0; i < 8; i++) {
        u16 hb = f2bf(vals[i]);
        h0[i] = hb; l0[i] = f2bf(vals[i] - bf2f(hb));
        u16 hb2 = f2bf(vals[8 + i]);
        h1[i] = hb2; l1[i] = f2bf(vals[8 + i] - bf2f(hb2));
      }
      *(u16x8*)&Ah[sr * LDT + sh] = h0;
      *(u16x8*)&Ah[sr * LDT + sh + 8] = h1;
      *(u16x8*)&Al[sr * LDT + sh] = l0;
      *(u16x8*)&Al[sr * LDT + sh + 8] = l1;
    }
    // ---- stage B ----
    {
      size_t base = (size_t)(n0 + sr) * K + k0 + sh;
      u16x8 b0 = *(const u16x8*)(Bph + base);
      u16x8 b1 = *(const u16x8*)(Bph + base + 8);
      *(u16x8*)&Bh[sr * LDT + sh] = b0;
      *(u16x8*)&Bh[sr * LDT + sh + 8] = b1;
      if (BSPLIT) {
        u16x8 c0 = *(const u16x8*)(Bpl + base);
        u16x8 c1 = *(const u16x8*)(Bpl + base + 8);
        *(u16x8*)&Bl[sr * LDT + sh] = c0;
        *(u16x8*)&Bl[sr * LDT + sh + 8] = c1;
      }
    }
    __syncthreads();
    // ---- fragments + MFMA ----
    const int fr = lane & 15;
    const int q8 = (lane >> 4) * 8;
    u16x8 af[4], bf[4];
#pragma unroll
    for (int i = 0; i < 4; i++) af[i] = *(const u16x8*)&Ah[(wm + i * 16 + fr) * LDT + q8];
#pragma unroll
    for (int j = 0; j < 4; j++) bf[j] = *(const u16x8*)&Bh[(wn + j * 16 + fr) * LDT + q8];
#pragma unroll
    for (int i = 0; i < 4; i++)
#pragma unroll
      for (int j = 0; j < 4; j++) acc[i][j] = mfma16(af[i], bf[j], acc[i][j]);
    if (ASPLIT) {
      u16x8 alf[4];
#pragma unroll
      for (int i = 0; i < 4; i++) alf[i] = *(const u16x8*)&Al[(wm + i * 16 + fr) * LDT + q8];
#pragma unroll
      for (int i = 0; i < 4; i++)
#pragma unroll
        for (int j = 0; j < 4; j++) acc[i][j] = mfma16(alf[i], bf[j], acc[i][j]);
    }
    if (BSPLIT) {
      u16x8 blf[4];
#pragma unroll
      for (int j = 0; j < 4; j++) blf[j] = *(const u16x8*)&Bl[(wn + j * 16 + fr) * LDT + q8];
#pragma unroll
      for (int i = 0; i < 4; i++)
#pragma unroll
        for (int j = 0; j < 4; j++) acc[i][j] = mfma16(af[i], blf[j], acc[i][j]);
    }
  }
  // ---- epilogue: C/D layout col=lane&15, row=(lane>>4)*4+reg (m89/m91 verified) ----
  const int fc = lane & 15;
  const int fr4 = (lane >> 4) * 4;
  if (FUSE) {
    // side: n0<512 -> S (0), n0==512 -> P (-1), n0>=640 -> O (1). Uniform per block.
    const int side = (n0 >= 640) ? 1 : (n0 < 512 ? 0 : -1);
    const int cb = n0 + wn + fc;
    float bvs[4];
#pragma unroll
    for (int j = 0; j < 4; j++) bvs[j] = biasf[cb + j * 16];
    __syncthreads();                 // staging LDS now dead; reuse Ah for score buf
    float* scb = (float*)Ah;         // [128 rows][2 wn-slots]
#pragma unroll
    for (int i = 0; i < 4; i++) {
#pragma unroll
      for (int rr = 0; rr < 4; rr++) {
        int rl = wm + i * 16 + fr4 + rr;
        int row = m0 + rl;
        float sc = 0.f;
        if (row < M) {
          const u16* arow = nullptr;
          if (side == 0) arow = auxp + (size_t)edges[(size_t)(r0 + row) * 2] * 512;
          else if (side == 1) arow = auxp + (size_t)edges[(size_t)(r0 + row) * 2 + 1] * 512;
#pragma unroll
          for (int j = 0; j < 4; j++) {
            int col = cb + j * 16;
            float v = acc[i][j][rr] + bvs[j];
            v = fmaxf(v, 0.f);
            if (side < 0) {
              Cf[(size_t)row * 128 + (col - 512)] = v;
            } else {
              int cc = col - (side ? 640 : 0);
              size_t ci = (size_t)row * 512 + cc;
              if (side) Ch2[ci] = f2bf(v);
              else Ch[ci] = f2bf(v);
              sc += v * bf2f(arow[cc]);
            }
          }
        }
        if (side >= 0) {
#pragma unroll
          for (int mm = 1; mm <= 8; mm <<= 1) sc += __shfl_xor(sc, mm, 64);
          if (fc == 0) scb[rl * 2 + (wn ? 1 : 0)] = sc;
        }
      }
    }
    __syncthreads();
    if (side >= 0 && tid < 128) {
      int row = m0 + tid;
      if (row < M) {
        float s = scb[tid * 2] + scb[tid * 2 + 1];
        atomicAdd(&scoresp[(side ? T_N : 0) + (r0 + row)], s);
      }
    }
    return;
  }
#pragma unroll
  for (int j = 0; j < 4; j++) {
    int col = n0 + wn + j * 16 + fc;
    float bv = biasf ? biasf[col] : 0.f;
#pragma unroll
    for (int i = 0; i < 4; i++) {
      int rbase = m0 + wm + i * 16 + fr4;
#pragma unroll
      for (int rr = 0; rr < 4; rr++) {
        int row = rbase + rr;
        if (row < M) {
          float v = acc[i][j][rr] + bv;
          if (RELU) v = fmaxf(v, 0.f);
          size_t ci = (size_t)row * ldc + col;
          if (OFLAGS & OF_F32) Cf[ci] = v;
          if (OFLAGS & OF_HI) {
            u16 h = f2bf(v);
            Ch[ci] = h;
            if (OFLAGS & OF_LO) Cl[ci] = f2bf(v - bf2f(h));
          }
        }
      }
    }
  }
}

// fp32 [K][N] -> bf16 hi(+lo) planes in BT form [N][K]. outl may be null.
__global__ void k_convT(const float* __restrict__ in, u16* __restrict__ outh,
                        u16* __restrict__ outl, int K, int N) {
  int idx = blockIdx.x * 256 + threadIdx.x;
  if (idx >= K * N) return;
  int n = idx / K, k = idx % K;
  float v = in[(size_t)k * N + n];
  u16 h = f2bf(v);
  outh[idx] = h;
  if (outl) outl[idx] = f2bf(v - bf2f(h));
}

// fp32 -> bf16 hi/lo planes, elementwise
__global__ void k_conv(const float* __restrict__ in, u16* __restrict__ outh,
                       u16* __restrict__ outl, int n) {
  int idx = blockIdx.x * 256 + threadIdx.x;
  if (idx >= n) return;
  float v = in[idx];
  u16 h = f2bf(v);
  outh[idx] = h;
  if (outl) outl[idx] = f2bf(v - bf2f(h));
}

// ---- weight folding (all fp32, trivial FLOPs) ----
__global__ void k_foldb1(const float* __restrict__ bp, const float* __restrict__ Ws,
                         const float* __restrict__ bs, float* __restrict__ bf1) {
  int n = blockIdx.x * 256 + threadIdx.x;
  if (n >= HID) return;
  float s = bs[n];
  for (int k = 0; k < HID; k++) s += bp[k] * Ws[(size_t)k * HID + n];
  bf1[n] = s;
}
__global__ void k_foldba(const float* __restrict__ bf1, const float* __restrict__ Ws,
                         float* __restrict__ ba) {
  int n = blockIdx.x * 256 + threadIdx.x;
  if (n >= HID) return;
  float s = 0.f;
  for (int k = 0; k < HID; k++) s += bf1[k] * Ws[(size_t)n * HID + k];
  ba[n] = s;
}
__global__ void k_foldwz(const float* __restrict__ Wf, const float* __restrict__ bs,
                         const float* __restrict__ bf1, float* __restrict__ wz,
                         float* __restrict__ bz) {
  int m = blockIdx.x * 256 + threadIdx.x;
  if (m < 128) {
    float s = 0.f;
    for (int n = 0; n < HID; n++) s += Wf[(size_t)m * HID + n] * bs[n];
    wz[m] = s;
  }
  if (m == 128) {
    float s = 0.f;
    for (int n = 0; n < HID; n++) s += bf1[n] * bs[n];
    *bz = s;
  }
}
// zs[o] = obj[o].wz + bz
__global__ void k_zsm(const float* __restrict__ obj, const float* __restrict__ wz,
                      const float* __restrict__ bz, float* __restrict__ zs, int rows) {
  int o = blockIdx.x * 4 + (threadIdx.x >> 6);
  int lane = threadIdx.x & 63;
  if (o >= rows) return;
  const float2* row = (const float2*)(obj + (size_t)o * 128);
  float2 v = row[lane];
  float2 w = ((const float2*)wz)[lane];
  float d = v.x * w.x + v.y * w.y;
  d = wave_sum(d);
  if (lane == 0) zs[o] = d + *bz;
}

__global__ void k_count(const int* __restrict__ edges, int* __restrict__ cnt) {
  int e = blockIdx.x * 256 + threadIdx.x;
  if (e >= 2 * T_N) return;
  int c = (e < T_N) ? edges[e * 2 + 0] : edges[(e - T_N) * 2 + 1];
  atomicAdd(cnt + c, 1);
}

__global__ void k_scan_a(const int* __restrict__ cnt, int* __restrict__ incl,
                         int* __restrict__ bsum) {
  __shared__ int sb[1024];
  int i = blockIdx.x * 1024 + threadIdx.x;
  int v = (i < O_N) ? cnt[i] : 0;
  sb[threadIdx.x] = v;
  __syncthreads();
  for (int ofs = 1; ofs < 1024; ofs <<= 1) {
    int t = (threadIdx.x >= ofs) ? sb[threadIdx.x - ofs] : 0;
    __syncthreads();
    sb[threadIdx.x] += t;
    __syncthreads();
  }
  if (i < O_N) incl[i] = sb[threadIdx.x];
  if (threadIdx.x == 1023) bsum[blockIdx.x] = sb[1023];
}

__global__ void k_scan_b(const int* __restrict__ bsum, int* __restrict__ bpre, int nb) {
  if (threadIdx.x == 0 && blockIdx.x == 0) {
    int run = 0;
    for (int b = 0; b < nb; b++) { bpre[b] = run; run += bsum[b]; }
  }
}

__global__ void k_scan_c(const int* __restrict__ incl, const int* __restrict__ cnt,
                         const int* __restrict__ bpre, int* __restrict__ excl,
                         int* __restrict__ cursor) {
  int i = blockIdx.x * 1024 + threadIdx.x;
  if (i >= O_N) return;
  int ex = incl[i] - cnt[i] + bpre[blockIdx.x];
  excl[i] = ex;
  cursor[i] = ex;
}

__global__ void k_fill(const int* __restrict__ edges, int* __restrict__ cursor,
                       int* __restrict__ csr) {
  int e = blockIdx.x * 256 + threadIdx.x;
  if (e >= 2 * T_N) return;
  int c = (e < T_N) ? edges[e * 2 + 0] : edges[(e - T_N) * 2 + 1];
  int pos = atomicAdd(cursor + c, 1);
  csr[pos] = e;
}

// scores[e] = zs[cand_idx[e]]  (base for fused-epilogue atomic accumulation)
__global__ void k_sinit(const int* __restrict__ edges, const float* __restrict__ zs,
                        float* __restrict__ scores) {
  int e = blockIdx.x * 256 + threadIdx.x;
  if (e >= 2 * T_N) return;
  int c = (e < T_N) ? edges[e * 2 + 0] : edges[(e - T_N) * 2 + 1];
  scores[e] = zs[c];
}

// score fix: scores[e] += cand_hi . (auxf - auxhi), per O-chunk
__global__ void k_fix(const u16* __restrict__ newShi, const u16* __restrict__ newOhi,
                      const u16* __restrict__ auxhi, const float* __restrict__ auxf,
                      const int* __restrict__ csr, const int* __restrict__ excl,
                      const int* __restrict__ cnt, float* __restrict__ scores,
                      int q0, int rows) {
  int ol = blockIdx.x * 4 + (threadIdx.x >> 6);
  int lane = threadIdx.x & 63;
  if (ol >= rows) return;
  int o = q0 + ol;
  int off = excl[o], deg = cnt[o];
  if (deg == 0) return;
  const f32x4* afp = (const f32x4*)(auxf + (size_t)ol * HID + lane * 8);
  f32x4 af0 = afp[0], af1 = afp[1];
  u16x8 ah = *(const u16x8*)(auxhi + (size_t)o * HID + lane * 8);
  float al[8];
#pragma unroll
  for (int k = 0; k < 4; k++) {
    al[k] = af0[k] - bf2f(ah[k]);
    al[4 + k] = af1[k] - bf2f(ah[4 + k]);
  }
  for (int i = 0; i < deg; i++) {
    int e = csr[off + i];
    const u16* cand =
        (e < T_N) ? newShi + (size_t)e * HID : newOhi + (size_t)(e - T_N) * HID;
    u16x8 ch = *(const u16x8*)(cand + lane * 8);
    float d = 0.f;
#pragma unroll
    for (int k = 0; k < 8; k++) d += bf2f(ch[k]) * al[k];
    d = wave_sum(d);
    if (lane == 0) scores[e] += d;  // each edge owned by exactly one object: no race
  }
}

// pool -> bf16 hi/lo planes (identical f2bf round points as the AMODE1 stage path)
__global__ void k_pool(const u16* __restrict__ newShi, const u16* __restrict__ newOhi,
                       const float* __restrict__ scores, const float* __restrict__ zs,
                       const int* __restrict__ csr, const int* __restrict__ excl,
                       const int* __restrict__ cnt, u16* __restrict__ pooledH,
                       u16* __restrict__ pooledL, int q0, int rows) {
  int ol = blockIdx.x * 4 + (threadIdx.x >> 6);
  int lane = threadIdx.x & 63;
  if (ol >= rows) return;
  int o = q0 + ol;
  int off = excl[o], deg = cnt[o];
  float zso = zs[o];
  float m = zso;
  for (int base = 0; base < deg; base += 64) {
    float s = (base + lane < deg) ? scores[csr[off + base + lane]] : -3.4e38f;
    m = fmaxf(m, s);
  }
#pragma unroll
  for (int x = 32; x >= 1; x >>= 1) m = fmaxf(m, __shfl_xor(m, x, 64));
  float denom = __expf(zso - m);
  float acc[8] = {0, 0, 0, 0, 0, 0, 0, 0};
  for (int i = 0; i < deg; i++) {
    int e = csr[off + i];
    float w = __expf(scores[e] - m);
    denom += w;
    const u16* cand =
        (e < T_N) ? newShi + (size_t)e * HID : newOhi + (size_t)(e - T_N) * HID;
    u16x8 cv = *(const u16x8*)(cand + lane * 8);
#pragma unroll
    for (int k = 0; k < 8; k++) acc[k] += w * bf2f(cv[k]);
  }
  float inv = 1.0f / denom;
  u16x8 ph, pl;
#pragma unroll
  for (int k = 0; k < 8; k++) {
    float v = acc[k] * inv;
    u16 h = f2bf(v);
    ph[k] = h;
    pl[k] = f2bf(v - bf2f(h));
  }
  *(u16x8*)(pooledH + (size_t)ol * HID + lane * 8) = ph;
  *(u16x8*)(pooledL + (size_t)ol * HID + lane * 8) = pl;
}

extern "C" void kernel_launch(void* const* d_in, const int* in_sizes, int n_in,
                              void* d_out, int out_size, void* d_ws, size_t ws_size,
                              hipStream_t stream) {
  const float* objf = (const float*)d_in[0];
  const float* predf = (const float*)d_in[1];
  const int* edges = (const int*)d_in[2];
  const float* n1w1f = (const float*)d_in[3];
  const float* n1b1f = (const float*)d_in[4];
  const float* n1w2f = (const float*)d_in[5];
  const float* n1b2f = (const float*)d_in[6];
  const float* n2w1f = (const float*)d_in[7];
  const float* n2b1f = (const float*)d_in[8];
  const float* n2w2f = (const float*)d_in[9];
  const float* n2b2f = (const float*)d_in[10];
  const float* projwf = (const float*)d_in[11];
  const float* projbf = (const float*)d_in[12];
  const float* simwf = (const float*)d_in[13];
  const float* simbf = (const float*)d_in[14];

  float* out_obj = (float*)d_out;                    // O x 128 fp32
  float* out_p = (float*)d_out + (size_t)O_N * 128;  // T x 128 fp32

  // ---- folded weights + fused M gemm with in-epilogue scores ----
  const long long FIXED = 267000000ll;
  long long budget = (long long)ws_size - FIXED;
  if (budget < 5000000ll) budget = 5000000ll;
  int rT, rOb, rFx;
  {
    long long r = budget / 2048; if (r > 50048) r = 50048; if (r < 1280) r = 1280;
    int n = (int)((T_N + r - 1) / r);
    rT = ((T_N + n - 1) / n + 127) & ~127;
  }
  {
    long long r = budget / 3072; if (r > 25024) r = 25024; if (r < 1280) r = 1280;
    int n = (int)((O_N + r - 1) / r);
    rOb = ((O_N + n - 1) / n + 127) & ~127;
  }
  {
    long long r = budget / 2048; if (r > 25024) r = 25024; if (r < 1280) r = 1280;
    int n = (int)((O_N + r - 1) / r);
    rFx = ((O_N + n - 1) / n + 127) & ~127;
  }
  const int nT = (T_N + rT - 1) / rT;
  const int nOb = (O_N + rOb - 1) / rOb;
  const int nFx = (O_N + rFx - 1) / rFx;
  size_t arena_sz = (size_t)rT * 2048;  // h1H + h1L
  if ((size_t)rFx * 2048 > arena_sz) arena_sz = (size_t)rFx * 2048;
  if ((size_t)rOb * 3072 > arena_sz) arena_sz = (size_t)rOb * 3072;
  arena_sz = (arena_sz + 4095) & ~(size_t)4095;

  char* ws = (char*)d_ws;
  size_t off = 0;
  u16* newShi = (u16*)(ws + off); off += (size_t)T_N * HID * 2;  // 102.4 MB
  u16* newOhi = (u16*)(ws + off); off += (size_t)T_N * HID * 2;  // 102.4 MB
  u16* auxhi = (u16*)(ws + off);  off += (size_t)O_N * HID * 2;  // 51.2 MB
  char* arena = ws + off; off += arena_sz;

  // phase M views
  u16* h1H = (u16*)arena;
  u16* h1L = (u16*)(arena + (size_t)rT * 1024);
  // fix-phase view
  float* auxfC = (float*)arena;
  // phase C views
  u16* pooledH = (u16*)arena;
  u16* pooledL = (u16*)(arena + (size_t)rOb * 1024);
  u16* h2c = (u16*)(arena + (size_t)rOb * 2048);

  float* scoresb = (float*)(ws + off); off += (size_t)2 * T_N * 4;
  float* zsb = (float*)(ws + off); off += (size_t)O_N * 4;
  int* cnt = (int*)(ws + off); off += (size_t)O_N * 4;
  int* incl = (int*)(ws + off); off += (size_t)O_N * 4;
  int* excl = (int*)(ws + off); off += (size_t)O_N * 4;
  int* cursor = (int*)(ws + off); off += (size_t)O_N * 4;
  int* csr = (int*)(ws + off); off += (size_t)2 * T_N * 4;
  int* bsum = (int*)(ws + off); off += 4096;
  int* bpre = (int*)(ws + off); off += 4096;
  u16* w1TH = (u16*)(ws + off); off += (size_t)K1 * HID * 2;
  u16* w1TL = (u16*)(ws + off); off += (size_t)K1 * HID * 2;
  u16* w2TH = (u16*)(ws + off); off += (size_t)1152 * HID * 2;
  u16* w2TL = (u16*)(ws + off); off += (size_t)1152 * HID * 2;
  u16* swTH = (u16*)(ws + off); off += (size_t)HID * HID * 2;
  u16* swTL = (u16*)(ws + off); off += (size_t)HID * HID * 2;
  u16* swRH = (u16*)(ws + off); off += (size_t)HID * HID * 2;
  u16* swRL = (u16*)(ws + off); off += (size_t)HID * HID * 2;
  u16* a2TH = (u16*)(ws + off); off += (size_t)HID * HID * 2;
  u16* a2TL = (u16*)(ws + off); off += (size_t)HID * HID * 2;
  u16* b2TH = (u16*)(ws + off); off += (size_t)128 * HID * 2;
  u16* b2TL = (u16*)(ws + off); off += (size_t)128 * HID * 2;
  float* Wf = (float*)(ws + off);  off += (size_t)128 * HID * 4;  // Wp@Ws
  float* Waf = (float*)(ws + off); off += (size_t)128 * HID * 4;  // Wf@Ws^T
  u16* WaTH = (u16*)(ws + off); off += (size_t)HID * 128 * 2;
  u16* WaTL = (u16*)(ws + off); off += (size_t)HID * 128 * 2;
  float* bf1 = (float*)(ws + off); off += 2048;
  float* baf = (float*)(ws + off); off += 2048;
  float* wzf = (float*)(ws + off); off += 512;
  float* bzf = (float*)(ws + off); off += 16;

  hipMemsetAsync(cnt, 0, O_N * sizeof(int), stream);

  // ---- weight planes ----
  k_convT<<<768, 256, 0, stream>>>(n1w1f, w1TH, w1TL, K1, HID);
  k_convT<<<2304, 256, 0, stream>>>(n1w2f, w2TH, w2TL, HID, 1152);
  k_convT<<<1024, 256, 0, stream>>>(simwf, swTH, swTL, HID, HID);
  k_conv<<<1024, 256, 0, stream>>>(simwf, swRH, swRL, HID * HID);  // Ws^T in BT form
  k_convT<<<1024, 256, 0, stream>>>(n2w1f, a2TH, a2TL, HID, HID);
  k_convT<<<256, 256, 0, stream>>>(n2w2f, b2TH, b2TL, HID, 128);

  // ---- CSR of cand_idx ----
  k_count<<<782, 256, 0, stream>>>(edges, cnt);
  k_scan_a<<<49, 1024, 0, stream>>>(cnt, incl, bsum);
  k_scan_b<<<1, 64, 0, stream>>>(bsum, bpre, 49);
  k_scan_c<<<49, 1024, 0, stream>>>(incl, cnt, bpre, excl, cursor);
  k_fill<<<782, 256, 0, stream>>>(edges, cursor, csr);

  // ---- weight folding ----
  {
    dim3 gW(1, 4);
    gemm_k<1, 1, 0, OF_F32, 0><<<gW, 256, 0, stream>>>(
        projwf, nullptr, swTH, swTL, nullptr,
        Wf, nullptr, nullptr, nullptr,
        128, HID, HID, HID, HID, nullptr, nullptr, nullptr, 0, nullptr, nullptr);
    gemm_k<1, 1, 0, OF_F32, 0><<<gW, 256, 0, stream>>>(
        Wf, nullptr, swRH, swRL, nullptr,
        Waf, nullptr, nullptr, nullptr,
        128, HID, HID, HID, HID, nullptr, nullptr, nullptr, 0, nullptr, nullptr);
    k_convT<<<256, 256, 0, stream>>>(Waf, WaTH, WaTL, 128, HID);
    k_foldb1<<<2, 256, 0, stream>>>(projbf, simwf, simbf, bf1);
    k_foldba<<<2, 256, 0, stream>>>(bf1, simwf, baf);
    k_foldwz<<<1, 256, 0, stream>>>(Wf, simbf, bf1, wzf, bzf);
  }

  // ---- phase B1 (folded): one full-grid gemm obj -> auxhi, plus zs matvec ----
  {
    dim3 gA((O_N + BM - 1) / BM, 4);
    gemm_k<1, 1, 0, OF_HI, 0><<<gA, 256, 0, stream>>>(
        objf, nullptr, WaTH, WaTL, baf,
        nullptr, auxhi, nullptr, nullptr,
        O_N, HID, 128, 128, HID, nullptr, nullptr, nullptr, 0, nullptr, nullptr);
    k_zsm<<<(O_N + 3) / 4, 256, 0, stream>>>(objf, wzf, bzf, zsb, O_N);
  }

  // ---- scores base = zs[cand] (fused epilogues accumulate on top) ----
  k_sinit<<<782, 256, 0, stream>>>(edges, zsb, scoresb);

  // ---- phase M: MLP1 (gather gemm) + fused N=1152 gemm w/ epilogue scores ----
  for (int ci = 0; ci < nT; ci++) {
    int r0 = ci * rT;
    int rows = (r0 + rT <= T_N) ? rT : (T_N - r0);
    dim3 g4((rows + BM - 1) / BM, 4);
    dim3 g9((rows + BM - 1) / BM, 9);
    gemm_k<2, 1, 1, OF_HI | OF_LO, 0><<<g4, 256, 0, stream>>>(
        nullptr, nullptr, w1TH, w1TL, n1b1f,
        nullptr, h1H, h1L, nullptr,
        rows, HID, K1, 0, HID, edges, objf, predf, r0, nullptr, nullptr);
    // fused: 0-511 -> newShi, 512-639 -> out_p, 640-1151 -> newOhi; scores atomic
    gemm_k<3, 1, 1, 0, 1><<<g9, 256, 0, stream>>>(
        h1H, h1L, w2TH, w2TL, n1b2f,
        out_p + (size_t)r0 * 128, newShi + (size_t)r0 * HID, nullptr,
        newOhi + (size_t)r0 * HID,
        rows, 1152, HID, HID, HID, edges, nullptr, nullptr, r0, auxhi, scoresb);
  }

  // ---- score fix: folded fp32 aux per O-chunk ----
  for (int ci = 0; ci < nFx; ci++) {
    int q0 = ci * rFx;
    int rows = (q0 + rFx <= O_N) ? rFx : (O_N - q0);
    dim3 g4((rows + BM - 1) / BM, 4);
    gemm_k<1, 1, 0, OF_F32, 0><<<g4, 256, 0, stream>>>(
        objf + (size_t)q0 * 128, nullptr, WaTH, WaTL, baf,
        auxfC, nullptr, nullptr, nullptr,
        rows, HID, 128, 128, HID, nullptr, nullptr, nullptr, 0, nullptr, nullptr);
    k_fix<<<(rows + 3) / 4, 256, 0, stream>>>(
        newShi, newOhi, auxhi, auxfC, csr, excl, cnt, scoresb, q0, rows);
  }

  // ---- phase C: pool (bf16 planes) -> MLP2, O-chunks ----
  for (int ci = 0; ci < nOb; ci++) {
    int q0 = ci * rOb;
    int rows = (q0 + rOb <= O_N) ? rOb : (O_N - q0);
    dim3 g4((rows + BM - 1) / BM, 4);
    dim3 g1((rows + BM - 1) / BM, 1);
    k_pool<<<(rows + 3) / 4, 256, 0, stream>>>(
        newShi, newOhi, scoresb, zsb, csr, excl, cnt, pooledH, pooledL, q0, rows);
    gemm_k<3, 1, 1, OF_HI, 0><<<g4, 256, 0, stream>>>(
        pooledH, pooledL, a2TH, a2TL, n2b1f,
        nullptr, h2c, nullptr, nullptr,
        rows, HID, HID, HID, HID, nullptr, nullptr, nullptr, 0, nullptr, nullptr);
    gemm_k<0, 1, 1, OF_F32, 0><<<g1, 256, 0, stream>>>(
        h2c, nullptr, b2TH, b2TL, n2b2f,
        out_obj + (size_t)q0 * 128, nullptr, nullptr, nullptr,
        rows, 128, HID, HID, 128, nullptr, nullptr, nullptr, 0, nullptr, nullptr);
  }

  (void)in_sizes; (void)n_in; (void)out_size;
}

// Round 8
// 1822.414 us; speedup vs baseline: 3.3216x; 1.0455x over previous
//
#include <hip/hip_runtime.h>

typedef unsigned short u16;
typedef unsigned int u32;
typedef u16 u16x8 __attribute__((ext_vector_type(8)));
typedef __bf16 bf16x8 __attribute__((ext_vector_type(8)));
typedef float f32x4 __attribute__((ext_vector_type(4)));

#define O_N 50000
#define T_N 100000
#define HID 512
#define K1 384
#define BM 128
#define BN 128
#define BK 32
#define LDT 40  // padded LDS stride (u16); 16B-quad stride 5 (odd) -> conflict-free b128

#define OF_F32 1
#define OF_HI 2
#define OF_LO 4

__device__ __forceinline__ u16 f2bf(float f) {
  u32 u = __float_as_uint(f);
  u += 0x7fffu + ((u >> 16) & 1u);
  return (u16)(u >> 16);
}
__device__ __forceinline__ float bf2f(u16 b) {
  return __uint_as_float(((u32)b) << 16);
}
__device__ __forceinline__ f32x4 mfma16(u16x8 a, u16x8 b, f32x4 c) {
  return __builtin_amdgcn_mfma_f32_16x16x32_bf16(
      __builtin_bit_cast(bf16x8, a), __builtin_bit_cast(bf16x8, b), c, 0, 0, 0);
}
__device__ __forceinline__ float wave_sum(float v) {
#pragma unroll
  for (int m = 32; m >= 1; m >>= 1) v += __shfl_xor(v, m, 64);
  return v;
}

// C[M x N] = act(A @ B + bias_f32). B given as bf16 hi(+lo) planes in BT form [N][K].
// AMODE: 0 = A bf16; 1 = A fp32 rows, split in stage; 2 = gathered fp32 t_in rows;
//        3 = A bf16 hi/lo planes.
// BSPLIT: stage B lo plane, add Ah*Bl term.
// FUSE: M-phase epilogue over N=1152 (see round-7 comment).
// Grid is 1D = nx*NY blocks; m204 bijective XCD-chunk swizzle groups all NY
// y-blocks of one x-tile (shared A-rows) onto one XCD so its L2 dedupes the
// A fetch (hardware round-robins blockIdx%8 across XCDs).
template <int AMODE, int BSPLIT, int RELU, int OFLAGS, int FUSE>
__global__ __launch_bounds__(256) void gemm_k(
    const void* __restrict__ Ap, const u16* __restrict__ Apl,
    const u16* __restrict__ Bph, const u16* __restrict__ Bpl,
    const float* __restrict__ biasf,
    float* __restrict__ Cf, u16* __restrict__ Ch, u16* __restrict__ Cl,
    u16* __restrict__ Ch2,
    int M, int N, int K, int lda, int ldc, int NY,
    const int* __restrict__ edges, const float* __restrict__ objf,
    const float* __restrict__ predf, int r0,
    const u16* __restrict__ auxp, float* __restrict__ scoresp) {
  const bool ASPLIT = (AMODE == 1 || AMODE == 2 || AMODE == 3);
  __shared__ u16 Ah[BM * LDT];
  __shared__ u16 Al[(AMODE == 1 || AMODE == 2 || AMODE == 3) ? BM * LDT : 8];
  __shared__ u16 Bh[BN * LDT];
  __shared__ u16 Bl[BSPLIT ? BN * LDT : 8];

  const int tid = threadIdx.x;
  const int lane = tid & 63;
  const int wave = tid >> 6;
  const int wm = (wave >> 1) * 64;
  const int wn = (wave & 1) * 64;
  // ---- XCD-chunked bijective swizzle (m204): orig%8 = XCD; give each XCD a
  // contiguous span of logical tiles. Identity when nwg<=8.
  int wg;
  {
    int nwg = gridDim.x, orig = blockIdx.x;
    int q = nwg >> 3, r = nwg & 7;
    int xcd = orig & 7, idx = orig >> 3;
    wg = (xcd < r ? xcd * (q + 1) : r * (q + 1) + (xcd - r) * q) + idx;
  }
  const int m0 = (wg / NY) * BM;
  const int n0 = (wg % NY) * BN;
  const int sr = tid >> 1;        // staged tile row
  const int sh = (tid & 1) * 16;  // k-offset half

  f32x4 acc[4][4] = {};

  for (int k0 = 0; k0 < K; k0 += BK) {
    __syncthreads();
    // ---- stage A ----
    if (AMODE == 0) {
      u16x8 v0 = {0, 0, 0, 0, 0, 0, 0, 0}, v1 = {0, 0, 0, 0, 0, 0, 0, 0};
      if (m0 + sr < M) {
        const u16* src = (const u16*)Ap + (size_t)(m0 + sr) * lda + k0 + sh;
        v0 = *(const u16x8*)src;
        v1 = *(const u16x8*)(src + 8);
      }
      *(u16x8*)&Ah[sr * LDT + sh] = v0;
      *(u16x8*)&Ah[sr * LDT + sh + 8] = v1;
    } else if (AMODE == 3) {
      u16x8 h0 = {0, 0, 0, 0, 0, 0, 0, 0}, h1 = h0, l0 = h0, l1 = h0;
      if (m0 + sr < M) {
        size_t base = (size_t)(m0 + sr) * lda + k0 + sh;
        h0 = *(const u16x8*)((const u16*)Ap + base);
        h1 = *(const u16x8*)((const u16*)Ap + base + 8);
        l0 = *(const u16x8*)(Apl + base);
        l1 = *(const u16x8*)(Apl + base + 8);
      }
      *(u16x8*)&Ah[sr * LDT + sh] = h0;
      *(u16x8*)&Ah[sr * LDT + sh + 8] = h1;
      *(u16x8*)&Al[sr * LDT + sh] = l0;
      *(u16x8*)&Al[sr * LDT + sh + 8] = l1;
    } else {  // AMODE 1 or 2: fp32 source, split into hi/lo
      float vals[16];
      if (m0 + sr < M) {
        const float* src;
        if (AMODE == 1) {
          src = (const float*)Ap + (size_t)(m0 + sr) * lda + k0 + sh;
        } else {
          int gr = r0 + m0 + sr;
          int col = k0 + sh;  // 16-col segment inside one source (128|128|128)
          if (col < 128) src = objf + (size_t)edges[gr * 2] * 128 + col;
          else if (col < 256) src = predf + (size_t)gr * 128 + (col - 128);
          else src = objf + (size_t)edges[gr * 2 + 1] * 128 + (col - 256);
        }
        const f32x4* s4 = (const f32x4*)src;
        f32x4 a0 = s4[0], a1 = s4[1], a2 = s4[2], a3 = s4[3];
#pragma unroll
        for (int i = 0; i < 4; i++) {
          vals[i] = a0[i]; vals[4 + i] = a1[i]; vals[8 + i] = a2[i]; vals[12 + i] = a3[i];
        }
      } else {
#pragma unroll
        for (int i = 0; i < 16; i++) vals[i] = 0.f;
      }
      u16x8 h0, h1, l0, l1;
#pragma unroll
      for (int i = 0; i < 8; i++) {
        u16 hb = f2bf(vals[i]);
        h0[i] = hb; l0[i] = f2bf(vals[i] - bf2f(hb));
        u16 hb2 = f2bf(vals[8 + i]);
        h1[i] = hb2; l1[i] = f2bf(vals[8 + i] - bf2f(hb2));
      }
      *(u16x8*)&Ah[sr * LDT + sh] = h0;
      *(u16x8*)&Ah[sr * LDT + sh + 8] = h1;
      *(u16x8*)&Al[sr * LDT + sh] = l0;
      *(u16x8*)&Al[sr * LDT + sh + 8] = l1;
    }
    // ---- stage B ----
    {
      size_t base = (size_t)(n0 + sr) * K + k0 + sh;
      u16x8 b0 = *(const u16x8*)(Bph + base);
      u16x8 b1 = *(const u16x8*)(Bph + base + 8);
      *(u16x8*)&Bh[sr * LDT + sh] = b0;
      *(u16x8*)&Bh[sr * LDT + sh + 8] = b1;
      if (BSPLIT) {
        u16x8 c0 = *(const u16x8*)(Bpl + base);
        u16x8 c1 = *(const u16x8*)(Bpl + base + 8);
        *(u16x8*)&Bl[sr * LDT + sh] = c0;
        *(u16x8*)&Bl[sr * LDT + sh + 8] = c1;
      }
    }
    __syncthreads();
    // ---- fragments + MFMA ----
    const int fr = lane & 15;
    const int q8 = (lane >> 4) * 8;
    u16x8 af[4], bf[4];
#pragma unroll
    for (int i = 0; i < 4; i++) af[i] = *(const u16x8*)&Ah[(wm + i * 16 + fr) * LDT + q8];
#pragma unroll
    for (int j = 0; j < 4; j++) bf[j] = *(const u16x8*)&Bh[(wn + j * 16 + fr) * LDT + q8];
#pragma unroll
    for (int i = 0; i < 4; i++)
#pragma unroll
      for (int j = 0; j < 4; j++) acc[i][j] = mfma16(af[i], bf[j], acc[i][j]);
    if (ASPLIT) {
      u16x8 alf[4];
#pragma unroll
      for (int i = 0; i < 4; i++) alf[i] = *(const u16x8*)&Al[(wm + i * 16 + fr) * LDT + q8];
#pragma unroll
      for (int i = 0; i < 4; i++)
#pragma unroll
        for (int j = 0; j < 4; j++) acc[i][j] = mfma16(alf[i], bf[j], acc[i][j]);
    }
    if (BSPLIT) {
      u16x8 blf[4];
#pragma unroll
      for (int j = 0; j < 4; j++) blf[j] = *(const u16x8*)&Bl[(wn + j * 16 + fr) * LDT + q8];
#pragma unroll
      for (int i = 0; i < 4; i++)
#pragma unroll
        for (int j = 0; j < 4; j++) acc[i][j] = mfma16(af[i], blf[j], acc[i][j]);
    }
  }
  // ---- epilogue: C/D layout col=lane&15, row=(lane>>4)*4+reg (m89/m91 verified) ----
  const int fc = lane & 15;
  const int fr4 = (lane >> 4) * 4;
  if (FUSE) {
    // side: n0<512 -> S (0), n0==512 -> P (-1), n0>=640 -> O (1). Uniform per block.
    const int side = (n0 >= 640) ? 1 : (n0 < 512 ? 0 : -1);
    const int cb = n0 + wn + fc;
    float bvs[4];
#pragma unroll
    for (int j = 0; j < 4; j++) bvs[j] = biasf[cb + j * 16];
    __syncthreads();                 // staging LDS now dead; reuse Ah for score buf
    float* scb = (float*)Ah;         // [128 rows][2 wn-slots]
#pragma unroll
    for (int i = 0; i < 4; i++) {
#pragma unroll
      for (int rr = 0; rr < 4; rr++) {
        int rl = wm + i * 16 + fr4 + rr;
        int row = m0 + rl;
        float sc = 0.f;
        if (row < M) {
          const u16* arow = nullptr;
          if (side == 0) arow = auxp + (size_t)edges[(size_t)(r0 + row) * 2] * 512;
          else if (side == 1) arow = auxp + (size_t)edges[(size_t)(r0 + row) * 2 + 1] * 512;
#pragma unroll
          for (int j = 0; j < 4; j++) {
            int col = cb + j * 16;
            float v = acc[i][j][rr] + bvs[j];
            v = fmaxf(v, 0.f);
            if (side < 0) {
              Cf[(size_t)row * 128 + (col - 512)] = v;
            } else {
              int cc = col - (side ? 640 : 0);
              size_t ci = (size_t)row * 512 + cc;
              if (side) Ch2[ci] = f2bf(v);
              else Ch[ci] = f2bf(v);
              sc += v * bf2f(arow[cc]);
            }
          }
        }
        if (side >= 0) {
#pragma unroll
          for (int mm = 1; mm <= 8; mm <<= 1) sc += __shfl_xor(sc, mm, 64);
          if (fc == 0) scb[rl * 2 + (wn ? 1 : 0)] = sc;
        }
      }
    }
    __syncthreads();
    if (side >= 0 && tid < 128) {
      int row = m0 + tid;
      if (row < M) {
        float s = scb[tid * 2] + scb[tid * 2 + 1];
        atomicAdd(&scoresp[(side ? T_N : 0) + (r0 + row)], s);
      }
    }
    return;
  }
#pragma unroll
  for (int j = 0; j < 4; j++) {
    int col = n0 + wn + j * 16 + fc;
    float bv = biasf ? biasf[col] : 0.f;
#pragma unroll
    for (int i = 0; i < 4; i++) {
      int rbase = m0 + wm + i * 16 + fr4;
#pragma unroll
      for (int rr = 0; rr < 4; rr++) {
        int row = rbase + rr;
        if (row < M) {
          float v = acc[i][j][rr] + bv;
          if (RELU) v = fmaxf(v, 0.f);
          size_t ci = (size_t)row * ldc + col;
          if (OFLAGS & OF_F32) Cf[ci] = v;
          if (OFLAGS & OF_HI) {
            u16 h = f2bf(v);
            Ch[ci] = h;
            if (OFLAGS & OF_LO) Cl[ci] = f2bf(v - bf2f(h));
          }
        }
      }
    }
  }
}

// fp32 [K][N] -> bf16 hi(+lo) planes in BT form [N][K]. outl may be null.
__global__ void k_convT(const float* __restrict__ in, u16* __restrict__ outh,
                        u16* __restrict__ outl, int K, int N) {
  int idx = blockIdx.x * 256 + threadIdx.x;
  if (idx >= K * N) return;
  int n = idx / K, k = idx % K;
  float v = in[(size_t)k * N + n];
  u16 h = f2bf(v);
  outh[idx] = h;
  if (outl) outl[idx] = f2bf(v - bf2f(h));
}

// fp32 -> bf16 hi/lo planes, elementwise
__global__ void k_conv(const float* __restrict__ in, u16* __restrict__ outh,
                       u16* __restrict__ outl, int n) {
  int idx = blockIdx.x * 256 + threadIdx.x;
  if (idx >= n) return;
  float v = in[idx];
  u16 h = f2bf(v);
  outh[idx] = h;
  if (outl) outl[idx] = f2bf(v - bf2f(h));
}

// ---- weight folding (all fp32, trivial FLOPs) ----
__global__ void k_foldb1(const float* __restrict__ bp, const float* __restrict__ Ws,
                         const float* __restrict__ bs, float* __restrict__ bf1) {
  int n = blockIdx.x * 256 + threadIdx.x;
  if (n >= HID) return;
  float s = bs[n];
  for (int k = 0; k < HID; k++) s += bp[k] * Ws[(size_t)k * HID + n];
  bf1[n] = s;
}
__global__ void k_foldba(const float* __restrict__ bf1, const float* __restrict__ Ws,
                         float* __restrict__ ba) {
  int n = blockIdx.x * 256 + threadIdx.x;
  if (n >= HID) return;
  float s = 0.f;
  for (int k = 0; k < HID; k++) s += bf1[k] * Ws[(size_t)n * HID + k];
  ba[n] = s;
}
__global__ void k_foldwz(const float* __restrict__ Wf, const float* __restrict__ bs,
                         const float* __restrict__ bf1, float* __restrict__ wz,
                         float* __restrict__ bz) {
  int m = blockIdx.x * 256 + threadIdx.x;
  if (m < 128) {
    float s = 0.f;
    for (int n = 0; n < HID; n++) s += Wf[(size_t)m * HID + n] * bs[n];
    wz[m] = s;
  }
  if (m == 128) {
    float s = 0.f;
    for (int n = 0; n < HID; n++) s += bf1[n] * bs[n];
    *bz = s;
  }
}
// zs[o] = obj[o].wz + bz
__global__ void k_zsm(const float* __restrict__ obj, const float* __restrict__ wz,
                      const float* __restrict__ bz, float* __restrict__ zs, int rows) {
  int o = blockIdx.x * 4 + (threadIdx.x >> 6);
  int lane = threadIdx.x & 63;
  if (o >= rows) return;
  const float2* row = (const float2*)(obj + (size_t)o * 128);
  float2 v = row[lane];
  float2 w = ((const float2*)wz)[lane];
  float d = v.x * w.x + v.y * w.y;
  d = wave_sum(d);
  if (lane == 0) zs[o] = d + *bz;
}

__global__ void k_count(const int* __restrict__ edges, int* __restrict__ cnt) {
  int e = blockIdx.x * 256 + threadIdx.x;
  if (e >= 2 * T_N) return;
  int c = (e < T_N) ? edges[e * 2 + 0] : edges[(e - T_N) * 2 + 1];
  atomicAdd(cnt + c, 1);
}

__global__ void k_scan_a(const int* __restrict__ cnt, int* __restrict__ incl,
                         int* __restrict__ bsum) {
  __shared__ int sb[1024];
  int i = blockIdx.x * 1024 + threadIdx.x;
  int v = (i < O_N) ? cnt[i] : 0;
  sb[threadIdx.x] = v;
  __syncthreads();
  for (int ofs = 1; ofs < 1024; ofs <<= 1) {
    int t = (threadIdx.x >= ofs) ? sb[threadIdx.x - ofs] : 0;
    __syncthreads();
    sb[threadIdx.x] += t;
    __syncthreads();
  }
  if (i < O_N) incl[i] = sb[threadIdx.x];
  if (threadIdx.x == 1023) bsum[blockIdx.x] = sb[1023];
}

__global__ void k_scan_b(const int* __restrict__ bsum, int* __restrict__ bpre, int nb) {
  if (threadIdx.x == 0 && blockIdx.x == 0) {
    int run = 0;
    for (int b = 0; b < nb; b++) { bpre[b] = run; run += bsum[b]; }
  }
}

__global__ void k_scan_c(const int* __restrict__ incl, const int* __restrict__ cnt,
                         const int* __restrict__ bpre, int* __restrict__ excl,
                         int* __restrict__ cursor) {
  int i = blockIdx.x * 1024 + threadIdx.x;
  if (i >= O_N) return;
  int ex = incl[i] - cnt[i] + bpre[blockIdx.x];
  excl[i] = ex;
  cursor[i] = ex;
}

__global__ void k_fill(const int* __restrict__ edges, int* __restrict__ cursor,
                       int* __restrict__ csr) {
  int e = blockIdx.x * 256 + threadIdx.x;
  if (e >= 2 * T_N) return;
  int c = (e < T_N) ? edges[e * 2 + 0] : edges[(e - T_N) * 2 + 1];
  int pos = atomicAdd(cursor + c, 1);
  csr[pos] = e;
}

// scores[e] = zs[cand_idx[e]]  (base for fused-epilogue atomic accumulation)
__global__ void k_sinit(const int* __restrict__ edges, const float* __restrict__ zs,
                        float* __restrict__ scores) {
  int e = blockIdx.x * 256 + threadIdx.x;
  if (e >= 2 * T_N) return;
  int c = (e < T_N) ? edges[e * 2 + 0] : edges[(e - T_N) * 2 + 1];
  scores[e] = zs[c];
}

// score fix: scores[e] += cand_hi . (auxf - auxhi), per O-chunk
__global__ void k_fix(const u16* __restrict__ newShi, const u16* __restrict__ newOhi,
                      const u16* __restrict__ auxhi, const float* __restrict__ auxf,
                      const int* __restrict__ csr, const int* __restrict__ excl,
                      const int* __restrict__ cnt, float* __restrict__ scores,
                      int q0, int rows) {
  int ol = blockIdx.x * 4 + (threadIdx.x >> 6);
  int lane = threadIdx.x & 63;
  if (ol >= rows) return;
  int o = q0 + ol;
  int off = excl[o], deg = cnt[o];
  if (deg == 0) return;
  const f32x4* afp = (const f32x4*)(auxf + (size_t)ol * HID + lane * 8);
  f32x4 af0 = afp[0], af1 = afp[1];
  u16x8 ah = *(const u16x8*)(auxhi + (size_t)o * HID + lane * 8);
  float al[8];
#pragma unroll
  for (int k = 0; k < 4; k++) {
    al[k] = af0[k] - bf2f(ah[k]);
    al[4 + k] = af1[k] - bf2f(ah[4 + k]);
  }
  for (int i = 0; i < deg; i++) {
    int e = csr[off + i];
    const u16* cand =
        (e < T_N) ? newShi + (size_t)e * HID : newOhi + (size_t)(e - T_N) * HID;
    u16x8 ch = *(const u16x8*)(cand + lane * 8);
    float d = 0.f;
#pragma unroll
    for (int k = 0; k < 8; k++) d += bf2f(ch[k]) * al[k];
    d = wave_sum(d);
    if (lane == 0) scores[e] += d;  // each edge owned by exactly one object: no race
  }
}

// pool -> bf16 hi/lo planes (identical f2bf round points as the AMODE1 stage path)
__global__ void k_pool(const u16* __restrict__ newShi, const u16* __restrict__ newOhi,
                       const float* __restrict__ scores, const float* __restrict__ zs,
                       const int* __restrict__ csr, const int* __restrict__ excl,
                       const int* __restrict__ cnt, u16* __restrict__ pooledH,
                       u16* __restrict__ pooledL, int q0, int rows) {
  int ol = blockIdx.x * 4 + (threadIdx.x >> 6);
  int lane = threadIdx.x & 63;
  if (ol >= rows) return;
  int o = q0 + ol;
  int off = excl[o], deg = cnt[o];
  float zso = zs[o];
  float m = zso;
  for (int base = 0; base < deg; base += 64) {
    float s = (base + lane < deg) ? scores[csr[off + base + lane]] : -3.4e38f;
    m = fmaxf(m, s);
  }
#pragma unroll
  for (int x = 32; x >= 1; x >>= 1) m = fmaxf(m, __shfl_xor(m, x, 64));
  float denom = __expf(zso - m);
  float acc[8] = {0, 0, 0, 0, 0, 0, 0, 0};
  for (int i = 0; i < deg; i++) {
    int e = csr[off + i];
    float w = __expf(scores[e] - m);
    denom += w;
    const u16* cand =
        (e < T_N) ? newShi + (size_t)e * HID : newOhi + (size_t)(e - T_N) * HID;
    u16x8 cv = *(const u16x8*)(cand + lane * 8);
#pragma unroll
    for (int k = 0; k < 8; k++) acc[k] += w * bf2f(cv[k]);
  }
  float inv = 1.0f / denom;
  u16x8 ph, pl;
#pragma unroll
  for (int k = 0; k < 8; k++) {
    float v = acc[k] * inv;
    u16 h = f2bf(v);
    ph[k] = h;
    pl[k] = f2bf(v - bf2f(h));
  }
  *(u16x8*)(pooledH + (size_t)ol * HID + lane * 8) = ph;
  *(u16x8*)(pooledL + (size_t)ol * HID + lane * 8) = pl;
}

extern "C" void kernel_launch(void* const* d_in, const int* in_sizes, int n_in,
                              void* d_out, int out_size, void* d_ws, size_t ws_size,
                              hipStream_t stream) {
  const float* objf = (const float*)d_in[0];
  const float* predf = (const float*)d_in[1];
  const int* edges = (const int*)d_in[2];
  const float* n1w1f = (const float*)d_in[3];
  const float* n1b1f = (const float*)d_in[4];
  const float* n1w2f = (const float*)d_in[5];
  const float* n1b2f = (const float*)d_in[6];
  const float* n2w1f = (const float*)d_in[7];
  const float* n2b1f = (const float*)d_in[8];
  const float* n2w2f = (const float*)d_in[9];
  const float* n2b2f = (const float*)d_in[10];
  const float* projwf = (const float*)d_in[11];
  const float* projbf = (const float*)d_in[12];
  const float* simwf = (const float*)d_in[13];
  const float* simbf = (const float*)d_in[14];

  float* out_obj = (float*)d_out;                    // O x 128 fp32
  float* out_p = (float*)d_out + (size_t)O_N * 128;  // T x 128 fp32

  // ---- folded weights + fused M gemm with in-epilogue scores ----
  const long long FIXED = 267000000ll;
  long long budget = (long long)ws_size - FIXED;
  if (budget < 5000000ll) budget = 5000000ll;
  int rT, rOb, rFx;
  {
    long long r = budget / 2048; if (r > 50048) r = 50048; if (r < 1280) r = 1280;
    int n = (int)((T_N + r - 1) / r);
    rT = ((T_N + n - 1) / n + 127) & ~127;
  }
  {
    long long r = budget / 3072; if (r > 25024) r = 25024; if (r < 1280) r = 1280;
    int n = (int)((O_N + r - 1) / r);
    rOb = ((O_N + n - 1) / n + 127) & ~127;
  }
  {
    long long r = budget / 2048; if (r > 25024) r = 25024; if (r < 1280) r = 1280;
    int n = (int)((O_N + r - 1) / r);
    rFx = ((O_N + n - 1) / n + 127) & ~127;
  }
  const int nT = (T_N + rT - 1) / rT;
  const int nOb = (O_N + rOb - 1) / rOb;
  const int nFx = (O_N + rFx - 1) / rFx;
  size_t arena_sz = (size_t)rT * 2048;  // h1H + h1L
  if ((size_t)rFx * 2048 > arena_sz) arena_sz = (size_t)rFx * 2048;
  if ((size_t)rOb * 3072 > arena_sz) arena_sz = (size_t)rOb * 3072;
  arena_sz = (arena_sz + 4095) & ~(size_t)4095;

  char* ws = (char*)d_ws;
  size_t off = 0;
  u16* newShi = (u16*)(ws + off); off += (size_t)T_N * HID * 2;  // 102.4 MB
  u16* newOhi = (u16*)(ws + off); off += (size_t)T_N * HID * 2;  // 102.4 MB
  u16* auxhi = (u16*)(ws + off);  off += (size_t)O_N * HID * 2;  // 51.2 MB
  char* arena = ws + off; off += arena_sz;

  // phase M views
  u16* h1H = (u16*)arena;
  u16* h1L = (u16*)(arena + (size_t)rT * 1024);
  // fix-phase view
  float* auxfC = (float*)arena;
  // phase C views
  u16* pooledH = (u16*)arena;
  u16* pooledL = (u16*)(arena + (size_t)rOb * 1024);
  u16* h2c = (u16*)(arena + (size_t)rOb * 2048);

  float* scoresb = (float*)(ws + off); off += (size_t)2 * T_N * 4;
  float* zsb = (float*)(ws + off); off += (size_t)O_N * 4;
  int* cnt = (int*)(ws + off); off += (size_t)O_N * 4;
  int* incl = (int*)(ws + off); off += (size_t)O_N * 4;
  int* excl = (int*)(ws + off); off += (size_t)O_N * 4;
  int* cursor = (int*)(ws + off); off += (size_t)O_N * 4;
  int* csr = (int*)(ws + off); off += (size_t)2 * T_N * 4;
  int* bsum = (int*)(ws + off); off += 4096;
  int* bpre = (int*)(ws + off); off += 4096;
  u16* w1TH = (u16*)(ws + off); off += (size_t)K1 * HID * 2;
  u16* w1TL = (u16*)(ws + off); off += (size_t)K1 * HID * 2;
  u16* w2TH = (u16*)(ws + off); off += (size_t)1152 * HID * 2;
  u16* w2TL = (u16*)(ws + off); off += (size_t)1152 * HID * 2;
  u16* swTH = (u16*)(ws + off); off += (size_t)HID * HID * 2;
  u16* swTL = (u16*)(ws + off); off += (size_t)HID * HID * 2;
  u16* swRH = (u16*)(ws + off); off += (size_t)HID * HID * 2;
  u16* swRL = (u16*)(ws + off); off += (size_t)HID * HID * 2;
  u16* a2TH = (u16*)(ws + off); off += (size_t)HID * HID * 2;
  u16* a2TL = (u16*)(ws + off); off += (size_t)HID * HID * 2;
  u16* b2TH = (u16*)(ws + off); off += (size_t)128 * HID * 2;
  u16* b2TL = (u16*)(ws + off); off += (size_t)128 * HID * 2;
  float* Wf = (float*)(ws + off);  off += (size_t)128 * HID * 4;  // Wp@Ws
  float* Waf = (float*)(ws + off); off += (size_t)128 * HID * 4;  // Wf@Ws^T
  u16* WaTH = (u16*)(ws + off); off += (size_t)HID * 128 * 2;
  u16* WaTL = (u16*)(ws + off); off += (size_t)HID * 128 * 2;
  float* bf1 = (float*)(ws + off); off += 2048;
  float* baf = (float*)(ws + off); off += 2048;
  float* wzf = (float*)(ws + off); off += 512;
  float* bzf = (float*)(ws + off); off += 16;

  hipMemsetAsync(cnt, 0, O_N * sizeof(int), stream);

  // ---- weight planes ----
  k_convT<<<768, 256, 0, stream>>>(n1w1f, w1TH, w1TL, K1, HID);
  k_convT<<<2304, 256, 0, stream>>>(n1w2f, w2TH, w2TL, HID, 1152);
  k_convT<<<1024, 256, 0, stream>>>(simwf, swTH, swTL, HID, HID);
  k_conv<<<1024, 256, 0, stream>>>(simwf, swRH, swRL, HID * HID);  // Ws^T in BT form
  k_convT<<<1024, 256, 0, stream>>>(n2w1f, a2TH, a2TL, HID, HID);
  k_convT<<<256, 256, 0, stream>>>(n2w2f, b2TH, b2TL, HID, 128);

  // ---- CSR of cand_idx ----
  k_count<<<782, 256, 0, stream>>>(edges, cnt);
  k_scan_a<<<49, 1024, 0, stream>>>(cnt, incl, bsum);
  k_scan_b<<<1, 64, 0, stream>>>(bsum, bpre, 49);
  k_scan_c<<<49, 1024, 0, stream>>>(incl, cnt, bpre, excl, cursor);
  k_fill<<<782, 256, 0, stream>>>(edges, cursor, csr);

  // ---- weight folding ----
  {
    gemm_k<1, 1, 0, OF_F32, 0><<<4, 256, 0, stream>>>(
        projwf, nullptr, swTH, swTL, nullptr,
        Wf, nullptr, nullptr, nullptr,
        128, HID, HID, HID, HID, 4, nullptr, nullptr, nullptr, 0, nullptr, nullptr);
    gemm_k<1, 1, 0, OF_F32, 0><<<4, 256, 0, stream>>>(
        Wf, nullptr, swRH, swRL, nullptr,
        Waf, nullptr, nullptr, nullptr,
        128, HID, HID, HID, HID, 4, nullptr, nullptr, nullptr, 0, nullptr, nullptr);
    k_convT<<<256, 256, 0, stream>>>(Waf, WaTH, WaTL, 128, HID);
    k_foldb1<<<2, 256, 0, stream>>>(projbf, simwf, simbf, bf1);
    k_foldba<<<2, 256, 0, stream>>>(bf1, simwf, baf);
    k_foldwz<<<1, 256, 0, stream>>>(Wf, simbf, bf1, wzf, bzf);
  }

  // ---- phase B1 (folded): one full-grid gemm obj -> auxhi, plus zs matvec ----
  {
    int gx = (O_N + BM - 1) / BM;
    gemm_k<1, 1, 0, OF_HI, 0><<<gx * 4, 256, 0, stream>>>(
        objf, nullptr, WaTH, WaTL, baf,
        nullptr, auxhi, nullptr, nullptr,
        O_N, HID, 128, 128, HID, 4, nullptr, nullptr, nullptr, 0, nullptr, nullptr);
    k_zsm<<<(O_N + 3) / 4, 256, 0, stream>>>(objf, wzf, bzf, zsb, O_N);
  }

  // ---- scores base = zs[cand] (fused epilogues accumulate on top) ----
  k_sinit<<<782, 256, 0, stream>>>(edges, zsb, scoresb);

  // ---- phase M: MLP1 (gather gemm) + fused N=1152 gemm w/ epilogue scores ----
  for (int ci = 0; ci < nT; ci++) {
    int r0 = ci * rT;
    int rows = (r0 + rT <= T_N) ? rT : (T_N - r0);
    int gx = (rows + BM - 1) / BM;
    gemm_k<2, 1, 1, OF_HI | OF_LO, 0><<<gx * 4, 256, 0, stream>>>(
        nullptr, nullptr, w1TH, w1TL, n1b1f,
        nullptr, h1H, h1L, nullptr,
        rows, HID, K1, 0, HID, 4, edges, objf, predf, r0, nullptr, nullptr);
    // fused: 0-511 -> newShi, 512-639 -> out_p, 640-1151 -> newOhi; scores atomic
    gemm_k<3, 1, 1, 0, 1><<<gx * 9, 256, 0, stream>>>(
        h1H, h1L, w2TH, w2TL, n1b2f,
        out_p + (size_t)r0 * 128, newShi + (size_t)r0 * HID, nullptr,
        newOhi + (size_t)r0 * HID,
        rows, 1152, HID, HID, HID, 9, edges, nullptr, nullptr, r0, auxhi, scoresb);
  }

  // ---- score fix: folded fp32 aux per O-chunk ----
  for (int ci = 0; ci < nFx; ci++) {
    int q0 = ci * rFx;
    int rows = (q0 + rFx <= O_N) ? rFx : (O_N - q0);
    int gx = (rows + BM - 1) / BM;
    gemm_k<1, 1, 0, OF_F32, 0><<<gx * 4, 256, 0, stream>>>(
        objf + (size_t)q0 * 128, nullptr, WaTH, WaTL, baf,
        auxfC, nullptr, nullptr, nullptr,
        rows, HID, 128, 128, HID, 4, nullptr, nullptr, nullptr, 0, nullptr, nullptr);
    k_fix<<<(rows + 3) / 4, 256, 0, stream>>>(
        newShi, newOhi, auxhi, auxfC, csr, excl, cnt, scoresb, q0, rows);
  }

  // ---- phase C: pool (bf16 planes) -> MLP2, O-chunks ----
  for (int ci = 0; ci < nOb; ci++) {
    int q0 = ci * rOb;
    int rows = (q0 + rOb <= O_N) ? rOb : (O_N - q0);
    int gx = (rows + BM - 1) / BM;
    k_pool<<<(rows + 3) / 4, 256, 0, stream>>>(
        newShi, newOhi, scoresb, zsb, csr, excl, cnt, pooledH, pooledL, q0, rows);
    gemm_k<3, 1, 1, OF_HI, 0><<<gx * 4, 256, 0, stream>>>(
        pooledH, pooledL, a2TH, a2TL, n2b1f,
        nullptr, h2c, nullptr, nullptr,
        rows, HID, HID, HID, HID, 4, nullptr, nullptr, nullptr, 0, nullptr, nullptr);
    gemm_k<0, 1, 1, OF_F32, 0><<<gx, 256, 0, stream>>>(
        h2c, nullptr, b2TH, b2TL, n2b2f,
        out_obj + (size_t)q0 * 128, nullptr, nullptr, nullptr,
        rows, 128, HID, HID, 128, 1, nullptr, nullptr, nullptr, 0, nullptr, nullptr);
  }

  (void)in_sizes; (void)n_in; (void)out_size;
}